// Round 1
// baseline (1165.627 us; speedup 1.0000x reference)
//
#include <hip/hip_runtime.h>
#include <math.h>

#define DMODEL 2048
#define NH     32
#define NKV    8
#define HDIM   64
#define GROUP  4

// ---------------------------------------------------------------------------
// Fused QKV projection GEMM (fp32, 128x128 tile, BK=32, 256 thr, 8x8 micro)
// with RoPE fused into the epilogue for Q and K.
// Grid: x = 24 tiles over concatenated N (2048 Q | 512 K | 512 V), y = T/128.
// ---------------------------------------------------------------------------
__global__ __launch_bounds__(256)
void gemm_qkv_rope(const float* __restrict__ X,
                   const float* __restrict__ Wq, const float* __restrict__ Wk,
                   const float* __restrict__ Wv,
                   const float* __restrict__ rsin, const float* __restrict__ rcos,
                   float* __restrict__ Qb, float* __restrict__ Kb,
                   float* __restrict__ Vb)
{
    __shared__ float As[32][132];   // [k][m] transposed, pad to 132 floats
    __shared__ float Bs[32][132];   // [k][n]

    const int t  = threadIdx.x;
    const int tx = t & 15, ty = t >> 4;
    const int m0 = blockIdx.y * 128;
    const int n0 = blockIdx.x * 128;

    const float* W; float* Out; int ldb; int noff; bool rope;
    if (n0 < 2048)      { W = Wq; Out = Qb; ldb = 2048; noff = n0;        rope = true;  }
    else if (n0 < 2560) { W = Wk; Out = Kb; ldb = 512;  noff = n0 - 2048; rope = true;  }
    else                { W = Wv; Out = Vb; ldb = 512;  noff = n0 - 2560; rope = false; }

    float acc[8][8];
    #pragma unroll
    for (int i = 0; i < 8; ++i)
        #pragma unroll
        for (int j = 0; j < 8; ++j) acc[i][j] = 0.0f;

    for (int k0 = 0; k0 < DMODEL; k0 += 32) {
        __syncthreads();
        // A tile: 128m x 32k = 1024 float4 (float4 along k), 4 per thread
        #pragma unroll
        for (int i = 0; i < 4; ++i) {
            int f  = t + i * 256;
            int m  = f >> 3;
            int kq = (f & 7) << 2;
            float4 av = *(const float4*)&X[(size_t)(m0 + m) * DMODEL + k0 + kq];
            As[kq + 0][m] = av.x; As[kq + 1][m] = av.y;
            As[kq + 2][m] = av.z; As[kq + 3][m] = av.w;
        }
        // B tile: 32k x 128n = 1024 float4 (float4 along n), 4 per thread
        #pragma unroll
        for (int i = 0; i < 4; ++i) {
            int f  = t + i * 256;
            int k  = f >> 5;
            int nq = (f & 31) << 2;
            *(float4*)&Bs[k][nq] =
                *(const float4*)&W[(size_t)(k0 + k) * ldb + noff + nq];
        }
        __syncthreads();
        #pragma unroll
        for (int kk = 0; kk < 32; ++kk) {
            float a[8], b[8];
            *(float4*)&a[0] = *(float4*)&As[kk][ty * 8];
            *(float4*)&a[4] = *(float4*)&As[kk][ty * 8 + 4];
            *(float4*)&b[0] = *(float4*)&Bs[kk][tx * 8];
            *(float4*)&b[4] = *(float4*)&Bs[kk][tx * 8 + 4];
            #pragma unroll
            for (int i = 0; i < 8; ++i)
                #pragma unroll
                for (int j = 0; j < 8; ++j)
                    acc[i][j] = fmaf(a[i], b[j], acc[i][j]);
        }
    }

    // epilogue: RoPE (interleaved pairs) for Q/K, then store
    #pragma unroll
    for (int i = 0; i < 8; ++i) {
        int m = m0 + ty * 8 + i;          // time index
        if (rope) {
            #pragma unroll
            for (int jp = 0; jp < 8; jp += 2) {
                int c  = noff + tx * 8 + jp;      // col within matrix
                int ia = (c & (HDIM - 1)) >> 1;   // pair index in head
                float sn = rsin[m * (HDIM / 2) + ia];
                float cs = rcos[m * (HDIM / 2) + ia];
                float x1 = acc[i][jp], x2 = acc[i][jp + 1];
                acc[i][jp]     = x1 * cs - x2 * sn;
                acc[i][jp + 1] = x1 * sn + x2 * cs;
            }
        }
        float4 o0 = make_float4(acc[i][0], acc[i][1], acc[i][2], acc[i][3]);
        float4 o1 = make_float4(acc[i][4], acc[i][5], acc[i][6], acc[i][7]);
        *(float4*)&Out[(size_t)m * ldb + noff + tx * 8]     = o0;
        *(float4*)&Out[(size_t)m * ldb + noff + tx * 8 + 4] = o1;
    }
}

// ---------------------------------------------------------------------------
// Output projection GEMM: C[T,2048] = A[T,2048] @ Wo[2048,2048]
// ---------------------------------------------------------------------------
__global__ __launch_bounds__(256)
void gemm_out(const float* __restrict__ A, const float* __restrict__ W,
              float* __restrict__ C)
{
    __shared__ float As[32][132];
    __shared__ float Bs[32][132];

    const int t  = threadIdx.x;
    const int tx = t & 15, ty = t >> 4;
    const int m0 = blockIdx.y * 128;
    const int n0 = blockIdx.x * 128;

    float acc[8][8];
    #pragma unroll
    for (int i = 0; i < 8; ++i)
        #pragma unroll
        for (int j = 0; j < 8; ++j) acc[i][j] = 0.0f;

    for (int k0 = 0; k0 < DMODEL; k0 += 32) {
        __syncthreads();
        #pragma unroll
        for (int i = 0; i < 4; ++i) {
            int f  = t + i * 256;
            int m  = f >> 3;
            int kq = (f & 7) << 2;
            float4 av = *(const float4*)&A[(size_t)(m0 + m) * DMODEL + k0 + kq];
            As[kq + 0][m] = av.x; As[kq + 1][m] = av.y;
            As[kq + 2][m] = av.z; As[kq + 3][m] = av.w;
        }
        #pragma unroll
        for (int i = 0; i < 4; ++i) {
            int f  = t + i * 256;
            int k  = f >> 5;
            int nq = (f & 31) << 2;
            *(float4*)&Bs[k][nq] =
                *(const float4*)&W[(size_t)(k0 + k) * DMODEL + n0 + nq];
        }
        __syncthreads();
        #pragma unroll
        for (int kk = 0; kk < 32; ++kk) {
            float a[8], b[8];
            *(float4*)&a[0] = *(float4*)&As[kk][ty * 8];
            *(float4*)&a[4] = *(float4*)&As[kk][ty * 8 + 4];
            *(float4*)&b[0] = *(float4*)&Bs[kk][tx * 8];
            *(float4*)&b[4] = *(float4*)&Bs[kk][tx * 8 + 4];
            #pragma unroll
            for (int i = 0; i < 8; ++i)
                #pragma unroll
                for (int j = 0; j < 8; ++j)
                    acc[i][j] = fmaf(a[i], b[j], acc[i][j]);
        }
    }

    #pragma unroll
    for (int i = 0; i < 8; ++i) {
        int m = m0 + ty * 8 + i;
        float4 o0 = make_float4(acc[i][0], acc[i][1], acc[i][2], acc[i][3]);
        float4 o1 = make_float4(acc[i][4], acc[i][5], acc[i][6], acc[i][7]);
        *(float4*)&C[(size_t)m * DMODEL + n0 + tx * 8]     = o0;
        *(float4*)&C[(size_t)m * DMODEL + n0 + tx * 8 + 4] = o1;
    }
}

// ---------------------------------------------------------------------------
// Flash-style attention with causal + sliding-window mask, GQA (4 Q heads per
// KV head). One block per (64-query tile, head); 64-key tiles; online softmax.
// 256 threads; 4q x 4k register micro-tile; row reduce via shfl over 16 lanes.
// ---------------------------------------------------------------------------
__global__ __launch_bounds__(256)
void attn_swa(const float* __restrict__ Q, const float* __restrict__ K,
              const float* __restrict__ V, float* __restrict__ O,
              const int* __restrict__ swa_ptr)
{
    __shared__ float Qs[64][68];
    __shared__ float Ks[64][68];
    __shared__ float Vs[64][68];
    __shared__ float Ps[64][68];

    const int h  = blockIdx.y;
    const int qt = blockIdx.x;
    const int q0 = qt * 64;
    const int hk = h / GROUP;
    const int t  = threadIdx.x;
    const int qg = t >> 4;        // 0..15  (4 q rows each)
    const int kg = t & 15;        // 0..15  (4 k cols / 4 d cols each)
    const int swa = *swa_ptr;
    const float scl = 0.125f;     // 1/sqrt(64)

    // load Q tile: 64 rows x 64 d = 1024 float4, 4 per thread
    #pragma unroll
    for (int i = 0; i < 4; ++i) {
        int f = t + i * 256;
        int r = f >> 4, d4 = (f & 15) << 2;
        *(float4*)&Qs[r][d4] =
            *(const float4*)&Q[(size_t)(q0 + r) * DMODEL + h * HDIM + d4];
    }

    float m_st[4], l_st[4], Oacc[4][4];
    #pragma unroll
    for (int i = 0; i < 4; ++i) {
        m_st[i] = -INFINITY; l_st[i] = 0.0f;
        #pragma unroll
        for (int j = 0; j < 4; ++j) Oacc[i][j] = 0.0f;
    }

    int kt_lo = 0;
    if (swa > 0) { int lo = q0 - swa; if (lo > 0) kt_lo = lo >> 6; }

    for (int kt = kt_lo; kt <= qt; ++kt) {
        const int k0 = kt * 64;
        __syncthreads();   // previous PV done before overwriting Ks/Vs
        #pragma unroll
        for (int i = 0; i < 4; ++i) {
            int f = t + i * 256;
            int r = f >> 4, d4 = (f & 15) << 2;
            *(float4*)&Ks[r][d4] =
                *(const float4*)&K[(size_t)(k0 + r) * (NKV * HDIM) + hk * HDIM + d4];
            *(float4*)&Vs[r][d4] =
                *(const float4*)&V[(size_t)(k0 + r) * (NKV * HDIM) + hk * HDIM + d4];
        }
        __syncthreads();

        // scores: 4q x 4k per thread over d=64
        float s[4][4];
        #pragma unroll
        for (int i = 0; i < 4; ++i)
            #pragma unroll
            for (int j = 0; j < 4; ++j) s[i][j] = 0.0f;

        #pragma unroll
        for (int d4 = 0; d4 < 16; ++d4) {
            float4 qv[4], kv[4];
            #pragma unroll
            for (int i = 0; i < 4; ++i) qv[i] = *(float4*)&Qs[qg * 4 + i][d4 * 4];
            #pragma unroll
            for (int j = 0; j < 4; ++j) kv[j] = *(float4*)&Ks[kg * 4 + j][d4 * 4];
            #pragma unroll
            for (int i = 0; i < 4; ++i)
                #pragma unroll
                for (int j = 0; j < 4; ++j)
                    s[i][j] += qv[i].x * kv[j].x + qv[i].y * kv[j].y +
                               qv[i].z * kv[j].z + qv[i].w * kv[j].w;
        }

        // mask + online softmax (row state replicated across the 16 kg lanes)
        float al[4];
        #pragma unroll
        for (int i = 0; i < 4; ++i) {
            int qq = q0 + qg * 4 + i;
            float rm = -INFINITY;
            #pragma unroll
            for (int j = 0; j < 4; ++j) {
                int kk = k0 + kg * 4 + j;
                int dl = qq - kk;
                bool ok = (dl >= 0) && (swa <= 0 || dl <= swa);
                float sv = ok ? s[i][j] * scl : -INFINITY;
                s[i][j] = sv;
                rm = fmaxf(rm, sv);
            }
            #pragma unroll
            for (int msk = 1; msk < 16; msk <<= 1)
                rm = fmaxf(rm, __shfl_xor(rm, msk));
            float mo = m_st[i];
            float mn = fmaxf(mo, rm);
            float a  = (mn == -INFINITY) ? 1.0f : __expf(mo - mn);
            float rs = 0.0f;
            #pragma unroll
            for (int j = 0; j < 4; ++j) {
                float p = (mn == -INFINITY) ? 0.0f : __expf(s[i][j] - mn);
                Ps[qg * 4 + i][kg * 4 + j] = p;
                rs += p;
            }
            #pragma unroll
            for (int msk = 1; msk < 16; msk <<= 1)
                rs += __shfl_xor(rs, msk);
            l_st[i] = l_st[i] * a + rs;
            m_st[i] = mn;
            al[i]   = a;
        }
        __syncthreads();   // Ps complete

        // PV: thread covers its 4 q rows x 4 d cols (d = kg*4..kg*4+3)
        #pragma unroll
        for (int i = 0; i < 4; ++i)
            #pragma unroll
            for (int j = 0; j < 4; ++j) Oacc[i][j] *= al[i];

        #pragma unroll 8
        for (int k = 0; k < 64; ++k) {
            float4 vv = *(float4*)&Vs[k][kg * 4];
            #pragma unroll
            for (int i = 0; i < 4; ++i) {
                float p = Ps[qg * 4 + i][k];
                Oacc[i][0] = fmaf(p, vv.x, Oacc[i][0]);
                Oacc[i][1] = fmaf(p, vv.y, Oacc[i][1]);
                Oacc[i][2] = fmaf(p, vv.z, Oacc[i][2]);
                Oacc[i][3] = fmaf(p, vv.w, Oacc[i][3]);
            }
        }
    }

    // final normalize + store: O[q][h*64 + kg*4 .. +3]
    #pragma unroll
    for (int i = 0; i < 4; ++i) {
        int qq = q0 + qg * 4 + i;
        float inv = 1.0f / l_st[i];
        float4 o = make_float4(Oacc[i][0] * inv, Oacc[i][1] * inv,
                               Oacc[i][2] * inv, Oacc[i][3] * inv);
        *(float4*)&O[(size_t)qq * DMODEL + h * HDIM + kg * 4] = o;
    }
}

extern "C" void kernel_launch(void* const* d_in, const int* in_sizes, int n_in,
                              void* d_out, int out_size, void* d_ws, size_t ws_size,
                              hipStream_t stream)
{
    const float* x    = (const float*)d_in[0];
    const float* Wq   = (const float*)d_in[1];
    const float* Wk   = (const float*)d_in[2];
    const float* Wv   = (const float*)d_in[3];
    const float* Wo   = (const float*)d_in[4];
    const float* rsin = (const float*)d_in[5];
    const float* rcos = (const float*)d_in[6];
    const int*   swa  = (const int*)d_in[7];

    const int T = in_sizes[0] / DMODEL;   // B=1

    float* ws = (float*)d_ws;
    float* Qb = ws;                                  // [T, 2048]
    float* Kb = Qb + (size_t)T * DMODEL;             // [T, 512]
    float* Vb = Kb + (size_t)T * (NKV * HDIM);       // [T, 512]
    float* Ab = Vb + (size_t)T * (NKV * HDIM);       // [T, 2048]

    dim3 g1((DMODEL + 2 * NKV * HDIM) / 128, T / 128);   // 24 x 16
    gemm_qkv_rope<<<g1, 256, 0, stream>>>(x, Wq, Wk, Wv, rsin, rcos, Qb, Kb, Vb);

    dim3 g2(T / 64, NH);                                  // 32 x 32
    attn_swa<<<g2, 256, 0, stream>>>(Qb, Kb, Vb, Ab, swa);

    dim3 g3(DMODEL / 128, T / 128);                       // 16 x 16
    gemm_out<<<g3, 256, 0, stream>>>(Ab, Wo, (float*)d_out);
}

// Round 2
// 371.648 us; speedup vs baseline: 3.1364x; 3.1364x over previous
//
#include <hip/hip_runtime.h>
#include <math.h>

#define DMODEL 2048
#define NH     32
#define NKV    8
#define HDIM   64
#define GROUP  4
#define KVW    (NKV * HDIM)   // 512

typedef short bf16x8 __attribute__((ext_vector_type(8)));
typedef float f32x4  __attribute__((ext_vector_type(4)));

__device__ __forceinline__ short f2bf(float f) {
    union { float f; unsigned u; } x; x.f = f;
    unsigned r = x.u + 0x7fffu + ((x.u >> 16) & 1u);   // RNE
    return (short)(r >> 16);
}
__device__ __forceinline__ float bf2f(short h) {
    union { unsigned u; float f; } x; x.u = ((unsigned)(unsigned short)h) << 16;
    return x.f;
}

typedef __attribute__((address_space(3))) void lds_void;
typedef const __attribute__((address_space(1))) void gbl_void;
__device__ __forceinline__ void gll16(const void* g, void* l) {
    __builtin_amdgcn_global_load_lds((gbl_void*)g, (lds_void*)l, 16, 0, 0);
}

// ---------------------------------------------------------------------------
// Elementwise fp32 -> (bf16 hi, bf16 lo) split
// ---------------------------------------------------------------------------
__global__ __launch_bounds__(256)
void split_f32(const float* __restrict__ in, short* __restrict__ oh,
               short* __restrict__ ol, int n4)
{
    int i = blockIdx.x * 256 + threadIdx.x;
    if (i >= n4) return;
    float4 v = ((const float4*)in)[i];
    short h0 = f2bf(v.x), h1 = f2bf(v.y), h2 = f2bf(v.z), h3 = f2bf(v.w);
    short l0 = f2bf(v.x - bf2f(h0)), l1 = f2bf(v.y - bf2f(h1));
    short l2 = f2bf(v.z - bf2f(h2)), l3 = f2bf(v.w - bf2f(h3));
    ((short4*)oh)[i] = make_short4(h0, h1, h2, h3);
    ((short4*)ol)[i] = make_short4(l0, l1, l2, l3);
}

// ---------------------------------------------------------------------------
// Transpose + split: W[K][N] fp32 -> WT_h/WT_l [N][K] bf16 (ldo = K)
// ---------------------------------------------------------------------------
__global__ __launch_bounds__(256)
void transpose_split_f32(const float* __restrict__ W, int K, int N,
                         short* __restrict__ oth, short* __restrict__ otl, int ldo)
{
    __shared__ float tile[32][33];
    const int bx = blockIdx.x, by = blockIdx.y;       // bx over N, by over K
    const int c = threadIdx.x & 31, r = threadIdx.x >> 5;
    #pragma unroll
    for (int it = 0; it < 4; ++it)
        tile[r + it * 8][c] = W[(size_t)(by * 32 + r + it * 8) * N + bx * 32 + c];
    __syncthreads();
    #pragma unroll
    for (int it = 0; it < 4; ++it) {
        int n = bx * 32 + r + it * 8;
        int k = by * 32 + c;
        float v = tile[c][r + it * 8];
        short h = f2bf(v), l = f2bf(v - bf2f(h));
        oth[(size_t)n * ldo + k] = h;
        otl[(size_t)n * ldo + k] = l;
    }
}

// ---------------------------------------------------------------------------
// bf16 transpose: in[R][C] -> out[C][R]   (for V -> V^T)
// ---------------------------------------------------------------------------
__global__ __launch_bounds__(256)
void transpose_bf16(const short* __restrict__ in, int R, int C,
                    short* __restrict__ out)
{
    __shared__ short tile[32][33];
    const int bx = blockIdx.x, by = blockIdx.y;       // bx over C, by over R
    const int c = threadIdx.x & 31, r = threadIdx.x >> 5;
    #pragma unroll
    for (int it = 0; it < 4; ++it)
        tile[r + it * 8][c] = in[(size_t)(by * 32 + r + it * 8) * C + bx * 32 + c];
    __syncthreads();
    #pragma unroll
    for (int it = 0; it < 4; ++it)
        out[(size_t)(bx * 32 + r + it * 8) * R + by * 32 + c] = tile[c][r + it * 8];
}

// ---------------------------------------------------------------------------
// 3-term bf16 MFMA GEMM: C[M][N] = (Ah+Al)[M][K] x (Bh+Bl)^T[N][K]
// 128x128 tile, BK=32, 4 waves (2x2 of 64x64), 16x16x32 MFMA.
// MODE 0: store fp32 C.  MODE 1: QKV epilogue (RoPE + bf16 to Q/K/V buffers).
// LDS 16B-slot XOR swizzle, both sides (staging source pre-swizzled).
// ---------------------------------------------------------------------------
template <int MODE>
__global__ __launch_bounds__(256)
void gemm3(const short* __restrict__ Ah, const short* __restrict__ Al,
           const short* __restrict__ Bh, const short* __restrict__ Bl,
           int K,
           float* __restrict__ C, int ldc,
           short* __restrict__ Qo, short* __restrict__ Ko, short* __restrict__ Vo,
           const float* __restrict__ rs, const float* __restrict__ rc)
{
    __shared__ __align__(16) short AhS[128 * 32];
    __shared__ __align__(16) short AlS[128 * 32];
    __shared__ __align__(16) short BhS[128 * 32];
    __shared__ __align__(16) short BlS[128 * 32];

    const int t = threadIdx.x, lane = t & 63, w = t >> 6;
    const int wr = (w >> 1) * 64, wc = (w & 1) * 64;
    const int m0 = blockIdx.y * 128, n0 = blockIdx.x * 128;

    f32x4 zero = {0.f, 0.f, 0.f, 0.f};
    f32x4 acc[4][4];
    #pragma unroll
    for (int i = 0; i < 4; ++i)
        #pragma unroll
        for (int j = 0; j < 4; ++j) acc[i][j] = zero;

    // staging: chunk c = w*2+i covers rows c*16 .. c*16+15 (1024B each)
    const int sr0 = (w * 2 + 0) * 16 + (lane >> 2);
    const int sr1 = (w * 2 + 1) * 16 + (lane >> 2);
    const int sc0 = (((lane & 3) ^ (sr0 & 3)) * 8);   // elements (16B granule)
    const int sc1 = (((lane & 3) ^ (sr1 & 3)) * 8);
    const size_t ga0 = (size_t)(m0 + sr0) * K + sc0;
    const size_t ga1 = (size_t)(m0 + sr1) * K + sc1;
    const size_t gb0 = (size_t)(n0 + sr0) * K + sc0;
    const size_t gb1 = (size_t)(n0 + sr1) * K + sc1;
    char* lA0 = (char*)AhS + (w * 2 + 0) * 1024;
    char* lA1 = (char*)AhS + (w * 2 + 1) * 1024;
    char* lAl0 = (char*)AlS + (w * 2 + 0) * 1024;
    char* lAl1 = (char*)AlS + (w * 2 + 1) * 1024;
    char* lB0 = (char*)BhS + (w * 2 + 0) * 1024;
    char* lB1 = (char*)BhS + (w * 2 + 1) * 1024;
    char* lBl0 = (char*)BlS + (w * 2 + 0) * 1024;
    char* lBl1 = (char*)BlS + (w * 2 + 1) * 1024;

    const int fr = lane & 15, fs = lane >> 4;

    for (int k0 = 0; k0 < K; k0 += 32) {
        __syncthreads();
        gll16(Ah + ga0 + k0, lA0);
        gll16(Ah + ga1 + k0, lA1);
        gll16(Al + ga0 + k0, lAl0);
        gll16(Al + ga1 + k0, lAl1);
        gll16(Bh + gb0 + k0, lB0);
        gll16(Bh + gb1 + k0, lB1);
        gll16(Bl + gb0 + k0, lBl0);
        gll16(Bl + gb1 + k0, lBl1);
        __syncthreads();

        bf16x8 fah[4], fal[4], fbh[4], fbl[4];
        #pragma unroll
        for (int i = 0; i < 4; ++i) {
            int ar = wr + i * 16 + fr;
            int aoff = ar * 64 + ((fs ^ (ar & 3)) << 4);
            fah[i] = *(const bf16x8*)((const char*)AhS + aoff);
            fal[i] = *(const bf16x8*)((const char*)AlS + aoff);
            int br = wc + i * 16 + fr;
            int boff = br * 64 + ((fs ^ (br & 3)) << 4);
            fbh[i] = *(const bf16x8*)((const char*)BhS + boff);
            fbl[i] = *(const bf16x8*)((const char*)BlS + boff);
        }
        #pragma unroll
        for (int i = 0; i < 4; ++i)
            #pragma unroll
            for (int j = 0; j < 4; ++j) {
                acc[i][j] = __builtin_amdgcn_mfma_f32_16x16x32_bf16(fah[i], fbh[j], acc[i][j], 0, 0, 0);
                acc[i][j] = __builtin_amdgcn_mfma_f32_16x16x32_bf16(fah[i], fbl[j], acc[i][j], 0, 0, 0);
                acc[i][j] = __builtin_amdgcn_mfma_f32_16x16x32_bf16(fal[i], fbh[j], acc[i][j], 0, 0, 0);
            }
    }

    const int g = lane >> 4;
    #pragma unroll
    for (int i = 0; i < 4; ++i)
        #pragma unroll
        for (int j = 0; j < 4; ++j)
            #pragma unroll
            for (int r = 0; r < 4; ++r) {
                int m = m0 + wr + i * 16 + g * 4 + r;
                int n = n0 + wc + j * 16 + fr;
                float v = acc[i][j][r];
                if (MODE == 0) {
                    C[(size_t)m * ldc + n] = v;
                } else {
                    if (n < 2048 + 512) {   // rope region (Q | K); uniform per block
                        float p = __shfl_xor(v, 1);
                        int pi = (n & (HDIM - 1)) >> 1;
                        float sn = rs[m * (HDIM / 2) + pi];
                        float cs = rc[m * (HDIM / 2) + pi];
                        v = ((lane & 1) == 0) ? (v * cs - p * sn) : (p * sn + v * cs);
                    }
                    short b = f2bf(v);
                    if (n < 2048)            Qo[(size_t)m * DMODEL + n] = b;
                    else if (n < 2048 + 512) Ko[(size_t)m * KVW + (n - 2048)] = b;
                    else                     Vo[(size_t)m * KVW + (n - 2560)] = b;
                }
            }
}

// ---------------------------------------------------------------------------
// Flash attention, bf16 MFMA 16x16x32, causal + sliding window, GQA.
// Block = (64 q-rows, head); 4 waves x 16 q-rows; 32-key tiles.
// K staged [key][64d] (8-slot XOR swz), V^T staged [d][32key] (4-slot swz),
// P bounced through per-wave LDS into A-fragment layout.
// Epilogue writes hi/lo bf16 split for the output GEMM.
// ---------------------------------------------------------------------------
__global__ __launch_bounds__(256)
void attn_mfma(const short* __restrict__ Qb, const short* __restrict__ Kb,
               const short* __restrict__ Vt, short* __restrict__ AoH,
               short* __restrict__ AoL, const int* __restrict__ swa_ptr, int T)
{
    __shared__ __align__(16) short Ks[32 * 64];
    __shared__ __align__(16) short Vs[64 * 32];
    __shared__ __align__(16) short Ps[4][16 * 32];

    const int h = blockIdx.y, qt = blockIdx.x;
    const int q0 = qt * 64, hk = h >> 2;
    const int t = threadIdx.x, lane = t & 63, w = t >> 6;
    const int swa = *swa_ptr;
    const int fr = lane & 15, g = lane >> 4;
    const int qrow = q0 + w * 16;

    // Q fragments (k-steps d0..31, d32..63), loop-invariant, in registers
    bf16x8 qf0, qf1;
    {
        const short* qp = Qb + (size_t)(qrow + fr) * DMODEL + h * HDIM + g * 8;
        qf0 = *(const bf16x8*)qp;
        qf1 = *(const bf16x8*)(qp + 32);
    }

    f32x4 zero = {0.f, 0.f, 0.f, 0.f};
    f32x4 oacc[4];
    #pragma unroll
    for (int dt = 0; dt < 4; ++dt) oacc[dt] = zero;
    float mreg[4] = {-INFINITY, -INFINITY, -INFINITY, -INFINITY};
    float lreg[4] = {0.f, 0.f, 0.f, 0.f};

    int kt_lo = 0;
    if (swa > 0) { int lo = q0 - swa; if (lo > 0) kt_lo = lo >> 5; }
    const int kt_hi = (q0 + 63) >> 5;

    // staging geometry
    const int krow = w * 8 + (lane >> 3);
    const int kcol = (((lane & 7) ^ (krow & 7)) * 8);
    const size_t kgbase = (size_t)krow * KVW + hk * HDIM + kcol;
    const int vrow = w * 16 + (lane >> 2);
    const int vcol = (((lane & 3) ^ (vrow & 3)) * 8);
    const size_t vgbase = (size_t)(hk * HDIM + vrow) * T + vcol;

    for (int kt = kt_lo; kt <= kt_hi; ++kt) {
        const int k0 = kt * 32;
        __syncthreads();
        gll16(Kb + (size_t)k0 * KVW + kgbase, (char*)Ks + w * 1024);
        gll16(Vt + vgbase + k0, (char*)Vs + w * 1024);
        __syncthreads();

        // S = Q K^T : two 16-key tiles, two k-steps over d
        f32x4 s0a = zero, s1a = zero;
        #pragma unroll
        for (int ks = 0; ks < 2; ++ks) {
            int slot = g + ks * 4;
            int key0 = fr, key1 = 16 + fr;
            bf16x8 kf0 = *(const bf16x8*)((const char*)Ks + key0 * 128 + ((slot ^ (key0 & 7)) << 4));
            bf16x8 kf1 = *(const bf16x8*)((const char*)Ks + key1 * 128 + ((slot ^ (key1 & 7)) << 4));
            bf16x8 qf = ks ? qf1 : qf0;
            s0a = __builtin_amdgcn_mfma_f32_16x16x32_bf16(qf, kf0, s0a, 0, 0, 0);
            s1a = __builtin_amdgcn_mfma_f32_16x16x32_bf16(qf, kf1, s1a, 0, 0, 0);
        }

        // mask + online softmax (row state per lane for its 4 rows)
        float alpha[4], p0v[4], p1v[4];
        #pragma unroll
        for (int r = 0; r < 4; ++r) {
            int i = qrow + g * 4 + r;
            int j0 = k0 + fr, j1 = k0 + 16 + fr;
            int d0 = i - j0, d1 = i - j1;
            float s0 = (d0 >= 0 && (swa <= 0 || d0 <= swa)) ? s0a[r] * 0.125f : -INFINITY;
            float s1 = (d1 >= 0 && (swa <= 0 || d1 <= swa)) ? s1a[r] * 0.125f : -INFINITY;
            float rm = fmaxf(s0, s1);
            rm = fmaxf(rm, __shfl_xor(rm, 1));
            rm = fmaxf(rm, __shfl_xor(rm, 2));
            rm = fmaxf(rm, __shfl_xor(rm, 4));
            rm = fmaxf(rm, __shfl_xor(rm, 8));
            float mo = mreg[r];
            float mn = fmaxf(mo, rm);
            float a, p0, p1;
            if (mn == -INFINITY) { a = 1.f; p0 = 0.f; p1 = 0.f; }
            else {
                a  = __expf(mo - mn);          // mo=-inf -> 0
                p0 = __expf(s0 - mn);          // s=-inf -> 0
                p1 = __expf(s1 - mn);
            }
            float rsum = p0 + p1;
            rsum += __shfl_xor(rsum, 1);
            rsum += __shfl_xor(rsum, 2);
            rsum += __shfl_xor(rsum, 4);
            rsum += __shfl_xor(rsum, 8);
            mreg[r] = mn;
            lreg[r] = lreg[r] * a + rsum;
            alpha[r] = a;
            p0v[r] = p0;
            p1v[r] = p1;
        }

        // write P (bf16) into per-wave LDS, A-fragment-friendly, swizzled
        #pragma unroll
        for (int r = 0; r < 4; ++r) {
            int row = g * 4 + r;
            int c0 = fr, c1 = 16 + fr;
            *(short*)((char*)Ps[w] + row * 64 + (((c0 >> 3) ^ (row & 3)) << 4) + ((c0 & 7) << 1)) = f2bf(p0v[r]);
            *(short*)((char*)Ps[w] + row * 64 + (((c1 >> 3) ^ (row & 3)) << 4) + ((c1 & 7) << 1)) = f2bf(p1v[r]);
        }
        __syncthreads();

        // rescale O then accumulate PV
        #pragma unroll
        for (int dt = 0; dt < 4; ++dt)
            #pragma unroll
            for (int r = 0; r < 4; ++r) oacc[dt][r] = oacc[dt][r] * alpha[r];

        {
            int prow = fr;
            bf16x8 pf = *(const bf16x8*)((const char*)Ps[w] + prow * 64 + ((g ^ (prow & 3)) << 4));
            #pragma unroll
            for (int dt = 0; dt < 4; ++dt) {
                int d = dt * 16 + fr;
                bf16x8 vf = *(const bf16x8*)((const char*)Vs + d * 64 + ((g ^ (d & 3)) << 4));
                oacc[dt] = __builtin_amdgcn_mfma_f32_16x16x32_bf16(pf, vf, oacc[dt], 0, 0, 0);
            }
        }
    }

    // epilogue: normalize, split hi/lo bf16, store
    float invl[4];
    #pragma unroll
    for (int r = 0; r < 4; ++r) invl[r] = 1.0f / lreg[r];
    #pragma unroll
    for (int dt = 0; dt < 4; ++dt)
        #pragma unroll
        for (int r = 0; r < 4; ++r) {
            int i = qrow + g * 4 + r;
            float v = oacc[dt][r] * invl[r];
            int col = h * HDIM + dt * 16 + fr;
            short hb = f2bf(v);
            short lb = f2bf(v - bf2f(hb));
            AoH[(size_t)i * DMODEL + col] = hb;
            AoL[(size_t)i * DMODEL + col] = lb;
        }
}

// ---------------------------------------------------------------------------
extern "C" void kernel_launch(void* const* d_in, const int* in_sizes, int n_in,
                              void* d_out, int out_size, void* d_ws, size_t ws_size,
                              hipStream_t stream)
{
    const float* x    = (const float*)d_in[0];
    const float* Wq   = (const float*)d_in[1];
    const float* Wk   = (const float*)d_in[2];
    const float* Wv   = (const float*)d_in[3];
    const float* Wo   = (const float*)d_in[4];
    const float* rsin = (const float*)d_in[5];
    const float* rcos = (const float*)d_in[6];
    const int*   swa  = (const int*)d_in[7];

    const int T = in_sizes[0] / DMODEL;   // 2048 (B=1)

    char* p = (char*)d_ws;
    short* WTh  = (short*)p; p += (size_t)3072 * 2048 * 2;   // [3072][2048] (Wq|Wk|Wv)^T hi
    short* WTl  = (short*)p; p += (size_t)3072 * 2048 * 2;
    short* WoTh = (short*)p; p += (size_t)2048 * 2048 * 2;
    short* WoTl = (short*)p; p += (size_t)2048 * 2048 * 2;
    short* Xh   = (short*)p; p += (size_t)T * DMODEL * 2;
    short* Xl   = (short*)p; p += (size_t)T * DMODEL * 2;
    short* Qbf  = (short*)p; p += (size_t)T * DMODEL * 2;
    short* Kbf  = (short*)p; p += (size_t)T * KVW * 2;
    short* Vbf  = (short*)p; p += (size_t)T * KVW * 2;
    short* Vt   = (short*)p; p += (size_t)T * KVW * 2;
    short* AoH  = Xh;   // alias: X dead after QKV gemm
    short* AoL  = Xl;

    // 1. split x into hi/lo bf16
    int n4 = T * DMODEL / 4;
    split_f32<<<(n4 + 255) / 256, 256, 0, stream>>>(x, Xh, Xl, n4);

    // 2. transpose+split weights into [N][K] bf16 hi/lo
    transpose_split_f32<<<dim3(2048 / 32, 2048 / 32), 256, 0, stream>>>(Wq, 2048, 2048, WTh, WTl, 2048);
    transpose_split_f32<<<dim3(512 / 32, 2048 / 32), 256, 0, stream>>>(Wk, 2048, 512, WTh + (size_t)2048 * 2048, WTl + (size_t)2048 * 2048, 2048);
    transpose_split_f32<<<dim3(512 / 32, 2048 / 32), 256, 0, stream>>>(Wv, 2048, 512, WTh + (size_t)2560 * 2048, WTl + (size_t)2560 * 2048, 2048);
    transpose_split_f32<<<dim3(2048 / 32, 2048 / 32), 256, 0, stream>>>(Wo, 2048, 2048, WoTh, WoTl, 2048);

    // 3. fused QKV projection (3-term bf16 MFMA) + RoPE epilogue
    gemm3<1><<<dim3(3072 / 128, T / 128), 256, 0, stream>>>(
        Xh, Xl, WTh, WTl, 2048, nullptr, 0, Qbf, Kbf, Vbf, rsin, rcos);

    // 4. V -> V^T [512][T]
    transpose_bf16<<<dim3(KVW / 32, T / 32), 256, 0, stream>>>(Vbf, T, KVW, Vt);

    // 5. attention
    attn_mfma<<<dim3(T / 64, NH), 256, 0, stream>>>(Qbf, Kbf, Vt, AoH, AoL, swa, T);

    // 6. output projection (3-term bf16 MFMA) -> fp32 out
    gemm3<0><<<dim3(2048 / 128, T / 128), 256, 0, stream>>>(
        AoH, AoL, WoTh, WoTl, 2048, (float*)d_out, 2048, nullptr, nullptr, nullptr, nullptr, nullptr);
}

// Round 7
// 354.322 us; speedup vs baseline: 3.2897x; 1.0489x over previous
//
#include <hip/hip_runtime.h>
#include <math.h>

#define DMODEL 2048
#define NH     32
#define NKV    8
#define HDIM   64
#define GROUP  4
#define KVW    (NKV * HDIM)   // 512

typedef short bf16x8 __attribute__((ext_vector_type(8)));
typedef float f32x4  __attribute__((ext_vector_type(4)));

__device__ __forceinline__ short f2bf(float f) {
    union { float f; unsigned u; } x; x.f = f;
    unsigned r = x.u + 0x7fffu + ((x.u >> 16) & 1u);   // RNE
    return (short)(r >> 16);
}
__device__ __forceinline__ float bf2f(short h) {
    union { unsigned u; float f; } x; x.u = ((unsigned)(unsigned short)h) << 16;
    return x.f;
}

typedef __attribute__((address_space(3))) void lds_void;
typedef const __attribute__((address_space(1))) void gbl_void;
__device__ __forceinline__ void gll16(const void* g, void* l) {
    __builtin_amdgcn_global_load_lds((gbl_void*)g, (lds_void*)l, 16, 0, 0);
}

// ---------------------------------------------------------------------------
// Elementwise fp32 -> (bf16 hi, bf16 lo) split
// ---------------------------------------------------------------------------
__global__ __launch_bounds__(256)
void split_f32(const float* __restrict__ in, short* __restrict__ oh,
               short* __restrict__ ol, int n4)
{
    int i = blockIdx.x * 256 + threadIdx.x;
    if (i >= n4) return;
    float4 v = ((const float4*)in)[i];
    short h0 = f2bf(v.x), h1 = f2bf(v.y), h2 = f2bf(v.z), h3 = f2bf(v.w);
    short l0 = f2bf(v.x - bf2f(h0)), l1 = f2bf(v.y - bf2f(h1));
    short l2 = f2bf(v.z - bf2f(h2)), l3 = f2bf(v.w - bf2f(h3));
    ((short4*)oh)[i] = make_short4(h0, h1, h2, h3);
    ((short4*)ol)[i] = make_short4(l0, l1, l2, l3);
}

// ---------------------------------------------------------------------------
// Transpose + split: W[K][N] fp32 -> WT_h/WT_l [N][K] bf16 (ldo = K)
// ---------------------------------------------------------------------------
__global__ __launch_bounds__(256)
void transpose_split_f32(const float* __restrict__ W, int K, int N,
                         short* __restrict__ oth, short* __restrict__ otl, int ldo)
{
    __shared__ float tile[32][33];
    const int bx = blockIdx.x, by = blockIdx.y;       // bx over N, by over K
    const int c = threadIdx.x & 31, r = threadIdx.x >> 5;
    #pragma unroll
    for (int it = 0; it < 4; ++it)
        tile[r + it * 8][c] = W[(size_t)(by * 32 + r + it * 8) * N + bx * 32 + c];
    __syncthreads();
    #pragma unroll
    for (int it = 0; it < 4; ++it) {
        int n = bx * 32 + r + it * 8;
        int k = by * 32 + c;
        float v = tile[c][r + it * 8];
        short h = f2bf(v), l = f2bf(v - bf2f(h));
        oth[(size_t)n * ldo + k] = h;
        otl[(size_t)n * ldo + k] = l;
    }
}

// ---------------------------------------------------------------------------
// bf16 transpose: in[R][C] -> out[C][R]   (for V -> V^T)
// ---------------------------------------------------------------------------
__global__ __launch_bounds__(256)
void transpose_bf16(const short* __restrict__ in, int R, int C,
                    short* __restrict__ out)
{
    __shared__ short tile[32][33];
    const int bx = blockIdx.x, by = blockIdx.y;       // bx over C, by over R
    const int c = threadIdx.x & 31, r = threadIdx.x >> 5;
    #pragma unroll
    for (int it = 0; it < 4; ++it)
        tile[r + it * 8][c] = in[(size_t)(by * 32 + r + it * 8) * C + bx * 32 + c];
    __syncthreads();
    #pragma unroll
    for (int it = 0; it < 4; ++it)
        out[(size_t)(bx * 32 + r + it * 8) * R + by * 32 + c] = tile[c][r + it * 8];
}

// ---------------------------------------------------------------------------
// 3-term bf16 MFMA GEMM: C[M][N] = (Ah+Al)[M][K] x (Bh+Bl)^T[N][K]
// 128x128 tile, BK=32, 4 waves (2x2 of 64x64), 16x16x32 MFMA.
// DOUBLE-BUFFERED LDS, prefetch-1-ahead, ONE barrier per K-step (T3 2-phase).
// MODE 0: store fp32 C.  MODE 1: QKV epilogue (RoPE + bf16 to Q/K/V buffers).
// ---------------------------------------------------------------------------
template <int MODE>
__global__ __launch_bounds__(256)
void gemm3(const short* __restrict__ Ah, const short* __restrict__ Al,
           const short* __restrict__ Bh, const short* __restrict__ Bl,
           int K,
           float* __restrict__ C, int ldc,
           short* __restrict__ Qo, short* __restrict__ Ko, short* __restrict__ Vo,
           const float* __restrict__ rs, const float* __restrict__ rc)
{
    __shared__ __align__(16) short AhS[2][128 * 32];   // 64 KB total (4 arrays x 2 bufs)
    __shared__ __align__(16) short AlS[2][128 * 32];
    __shared__ __align__(16) short BhS[2][128 * 32];
    __shared__ __align__(16) short BlS[2][128 * 32];

    const int t = threadIdx.x, lane = t & 63, w = t >> 6;
    const int wr = (w >> 1) * 64, wc = (w & 1) * 64;
    const int m0 = blockIdx.y * 128, n0 = blockIdx.x * 128;

    f32x4 zero = {0.f, 0.f, 0.f, 0.f};
    f32x4 acc[4][4];
    #pragma unroll
    for (int i = 0; i < 4; ++i)
        #pragma unroll
        for (int j = 0; j < 4; ++j) acc[i][j] = zero;

    // staging: chunk c = w*2+i covers rows c*16 .. c*16+15 (1024B each)
    const int sr0 = (w * 2 + 0) * 16 + (lane >> 2);
    const int sr1 = (w * 2 + 1) * 16 + (lane >> 2);
    const int sc0 = (((lane & 3) ^ (sr0 & 3)) * 8);   // elements (16B granule)
    const int sc1 = (((lane & 3) ^ (sr1 & 3)) * 8);
    const size_t ga0 = (size_t)(m0 + sr0) * K + sc0;
    const size_t ga1 = (size_t)(m0 + sr1) * K + sc1;
    const size_t gb0 = (size_t)(n0 + sr0) * K + sc0;
    const size_t gb1 = (size_t)(n0 + sr1) * K + sc1;
    const int co0 = (w * 2 + 0) * 1024;
    const int co1 = (w * 2 + 1) * 1024;

    const int fr = lane & 15, fs = lane >> 4;

    auto stage = [&](int k0, int p) {
        gll16(Ah + ga0 + k0, (char*)AhS[p] + co0);
        gll16(Ah + ga1 + k0, (char*)AhS[p] + co1);
        gll16(Al + ga0 + k0, (char*)AlS[p] + co0);
        gll16(Al + ga1 + k0, (char*)AlS[p] + co1);
        gll16(Bh + gb0 + k0, (char*)BhS[p] + co0);
        gll16(Bh + gb1 + k0, (char*)BhS[p] + co1);
        gll16(Bl + gb0 + k0, (char*)BlS[p] + co0);
        gll16(Bl + gb1 + k0, (char*)BlS[p] + co1);
    };

    const int nsteps = K >> 5;
    stage(0, 0);

    for (int s = 0; s < nsteps; ++s) {
        const int p = s & 1;
        __syncthreads();                 // drains prefetch for step s; bufs[p^1] free
        if (s + 1 < nsteps) stage((s + 1) << 5, p ^ 1);

        bf16x8 fah[4], fal[4], fbh[4], fbl[4];
        #pragma unroll
        for (int i = 0; i < 4; ++i) {
            int ar = wr + i * 16 + fr;
            int aoff = ar * 64 + ((fs ^ (ar & 3)) << 4);
            fah[i] = *(const bf16x8*)((const char*)AhS[p] + aoff);
            fal[i] = *(const bf16x8*)((const char*)AlS[p] + aoff);
            int br = wc + i * 16 + fr;
            int boff = br * 64 + ((fs ^ (br & 3)) << 4);
            fbh[i] = *(const bf16x8*)((const char*)BhS[p] + boff);
            fbl[i] = *(const bf16x8*)((const char*)BlS[p] + boff);
        }
        #pragma unroll
        for (int i = 0; i < 4; ++i)
            #pragma unroll
            for (int j = 0; j < 4; ++j) {
                acc[i][j] = __builtin_amdgcn_mfma_f32_16x16x32_bf16(fah[i], fbh[j], acc[i][j], 0, 0, 0);
                acc[i][j] = __builtin_amdgcn_mfma_f32_16x16x32_bf16(fah[i], fbl[j], acc[i][j], 0, 0, 0);
                acc[i][j] = __builtin_amdgcn_mfma_f32_16x16x32_bf16(fal[i], fbh[j], acc[i][j], 0, 0, 0);
            }
    }

    const int g = lane >> 4;
    #pragma unroll
    for (int i = 0; i < 4; ++i)
        #pragma unroll
        for (int j = 0; j < 4; ++j)
            #pragma unroll
            for (int r = 0; r < 4; ++r) {
                int m = m0 + wr + i * 16 + g * 4 + r;
                int n = n0 + wc + j * 16 + fr;
                float v = acc[i][j][r];
                if (MODE == 0) {
                    C[(size_t)m * ldc + n] = v;
                } else {
                    if (n < 2048 + 512) {   // rope region (Q | K); uniform per block
                        float pp = __shfl_xor(v, 1);
                        int pi = (n & (HDIM - 1)) >> 1;
                        float sn = rs[m * (HDIM / 2) + pi];
                        float cs = rc[m * (HDIM / 2) + pi];
                        v = ((lane & 1) == 0) ? (v * cs - pp * sn) : (pp * sn + v * cs);
                    }
                    short b = f2bf(v);
                    if (n < 2048)            Qo[(size_t)m * DMODEL + n] = b;
                    else if (n < 2048 + 512) Ko[(size_t)m * KVW + (n - 2048)] = b;
                    else                     Vo[(size_t)m * KVW + (n - 2560)] = b;
                }
            }
}

// ---------------------------------------------------------------------------
// Flash attention, bf16 MFMA 16x16x32, causal + sliding window, GQA.
// Block = (64 q-rows, head); 4 waves x 16 q-rows; 32-key tiles.
// Double-buffered K/V staging, prefetch-1-ahead, ONE barrier per tile.
// Ps is per-wave private (no barrier needed around it).
// Epilogue writes hi/lo bf16 split for the output GEMM.
// ---------------------------------------------------------------------------
__global__ __launch_bounds__(256)
void attn_mfma(const short* __restrict__ Qb, const short* __restrict__ Kb,
               const short* __restrict__ Vt, short* __restrict__ AoH,
               short* __restrict__ AoL, const int* __restrict__ swa_ptr, int T)
{
    __shared__ __align__(16) short Ks[2][32 * 64];   // 2 x 4 KB
    __shared__ __align__(16) short Vs[2][64 * 32];   // 2 x 4 KB
    __shared__ __align__(16) short Ps[4][16 * 32];   // 4 KB (per-wave)

    const int h = blockIdx.y, qt = blockIdx.x;
    const int q0 = qt * 64, hk = h >> 2;
    const int t = threadIdx.x, lane = t & 63, w = t >> 6;
    const int swa = *swa_ptr;
    const int fr = lane & 15, g = lane >> 4;
    const int qrow = q0 + w * 16;

    // Q fragments (k-steps d0..31, d32..63), loop-invariant, in registers
    bf16x8 qf0, qf1;
    {
        const short* qp = Qb + (size_t)(qrow + fr) * DMODEL + h * HDIM + g * 8;
        qf0 = *(const bf16x8*)qp;
        qf1 = *(const bf16x8*)(qp + 32);
    }

    f32x4 zero = {0.f, 0.f, 0.f, 0.f};
    f32x4 oacc[4];
    #pragma unroll
    for (int dt = 0; dt < 4; ++dt) oacc[dt] = zero;
    float mreg[4] = {-INFINITY, -INFINITY, -INFINITY, -INFINITY};
    float lreg[4] = {0.f, 0.f, 0.f, 0.f};

    int kt_lo = 0;
    if (swa > 0) { int lo = q0 - swa; if (lo > 0) kt_lo = lo >> 5; }
    const int kt_hi = (q0 + 63) >> 5;

    // staging geometry
    const int krow = w * 8 + (lane >> 3);
    const int kcol = (((lane & 7) ^ (krow & 7)) * 8);
    const size_t kgbase = (size_t)krow * KVW + hk * HDIM + kcol;
    const int vrow = w * 16 + (lane >> 2);
    const int vcol = (((lane & 3) ^ (vrow & 3)) * 8);
    const size_t vgbase = (size_t)(hk * HDIM + vrow) * T + vcol;

    auto stage = [&](int kt, int p) {
        gll16(Kb + (size_t)(kt * 32) * KVW + kgbase, (char*)Ks[p] + w * 1024);
        gll16(Vt + vgbase + kt * 32, (char*)Vs[p] + w * 1024);
    };

    stage(kt_lo, 0);

    for (int kt = kt_lo; kt <= kt_hi; ++kt) {
        const int k0 = kt * 32;
        const int p = (kt - kt_lo) & 1;
        __syncthreads();                 // prefetch for kt landed; bufs[p^1] free
        if (kt + 1 <= kt_hi) stage(kt + 1, p ^ 1);

        // S = Q K^T : two 16-key tiles, two k-steps over d
        f32x4 s0a = zero, s1a = zero;
        #pragma unroll
        for (int ks = 0; ks < 2; ++ks) {
            int slot = g + ks * 4;
            int key0 = fr, key1 = 16 + fr;
            bf16x8 kf0 = *(const bf16x8*)((const char*)Ks[p] + key0 * 128 + ((slot ^ (key0 & 7)) << 4));
            bf16x8 kf1 = *(const bf16x8*)((const char*)Ks[p] + key1 * 128 + ((slot ^ (key1 & 7)) << 4));
            bf16x8 qf = ks ? qf1 : qf0;
            s0a = __builtin_amdgcn_mfma_f32_16x16x32_bf16(qf, kf0, s0a, 0, 0, 0);
            s1a = __builtin_amdgcn_mfma_f32_16x16x32_bf16(qf, kf1, s1a, 0, 0, 0);
        }

        // interior tile? (whole wave passes causal+window) -> skip masking
        const bool full = (k0 + 31 <= qrow) && (swa <= 0 || (qrow + 15 - k0) <= swa);

        // mask + online softmax (row state per lane for its 4 rows)
        float alpha[4], p0v[4], p1v[4];
        #pragma unroll
        for (int r = 0; r < 4; ++r) {
            float s0, s1;
            if (full) {
                s0 = s0a[r] * 0.125f;
                s1 = s1a[r] * 0.125f;
            } else {
                int i = qrow + g * 4 + r;
                int j0 = k0 + fr, j1 = k0 + 16 + fr;
                int d0 = i - j0, d1 = i - j1;
                s0 = (d0 >= 0 && (swa <= 0 || d0 <= swa)) ? s0a[r] * 0.125f : -INFINITY;
                s1 = (d1 >= 0 && (swa <= 0 || d1 <= swa)) ? s1a[r] * 0.125f : -INFINITY;
            }
            float rm = fmaxf(s0, s1);
            rm = fmaxf(rm, __shfl_xor(rm, 1));
            rm = fmaxf(rm, __shfl_xor(rm, 2));
            rm = fmaxf(rm, __shfl_xor(rm, 4));
            rm = fmaxf(rm, __shfl_xor(rm, 8));
            float mo = mreg[r];
            float mn = fmaxf(mo, rm);
            float a, p0, p1;
            if (mn == -INFINITY) { a = 1.f; p0 = 0.f; p1 = 0.f; }
            else {
                a  = __expf(mo - mn);          // mo=-inf -> 0
                p0 = __expf(s0 - mn);          // s=-inf -> 0
                p1 = __expf(s1 - mn);
            }
            float rsum = p0 + p1;
            rsum += __shfl_xor(rsum, 1);
            rsum += __shfl_xor(rsum, 2);
            rsum += __shfl_xor(rsum, 4);
            rsum += __shfl_xor(rsum, 8);
            mreg[r] = mn;
            lreg[r] = lreg[r] * a + rsum;
            alpha[r] = a;
            p0v[r] = p0;
            p1v[r] = p1;
        }

        // write P (bf16) into per-wave LDS, A-fragment-friendly, swizzled
        #pragma unroll
        for (int r = 0; r < 4; ++r) {
            int row = g * 4 + r;
            int c0 = fr, c1 = 16 + fr;
            *(short*)((char*)Ps[w] + row * 64 + (((c0 >> 3) ^ (row & 3)) << 4) + ((c0 & 7) << 1)) = f2bf(p0v[r]);
            *(short*)((char*)Ps[w] + row * 64 + (((c1 >> 3) ^ (row & 3)) << 4) + ((c1 & 7) << 1)) = f2bf(p1v[r]);
        }
        // Ps[w] is written and read by wave w only: no barrier needed
        // (compiler inserts lgkmcnt for the same-wave LDS RAW dependency)

        // rescale O then accumulate PV
        #pragma unroll
        for (int dt = 0; dt < 4; ++dt)
            #pragma unroll
            for (int r = 0; r < 4; ++r) oacc[dt][r] = oacc[dt][r] * alpha[r];

        {
            int prow = fr;
            bf16x8 pf = *(const bf16x8*)((const char*)Ps[w] + prow * 64 + ((g ^ (prow & 3)) << 4));
            #pragma unroll
            for (int dt = 0; dt < 4; ++dt) {
                int d = dt * 16 + fr;
                bf16x8 vf = *(const bf16x8*)((const char*)Vs[p] + d * 64 + ((g ^ (d & 3)) << 4));
                oacc[dt] = __builtin_amdgcn_mfma_f32_16x16x32_bf16(pf, vf, oacc[dt], 0, 0, 0);
            }
        }
    }

    // epilogue: normalize, split hi/lo bf16, store
    float invl[4];
    #pragma unroll
    for (int r = 0; r < 4; ++r) invl[r] = 1.0f / lreg[r];
    #pragma unroll
    for (int dt = 0; dt < 4; ++dt)
        #pragma unroll
        for (int r = 0; r < 4; ++r) {
            int i = qrow + g * 4 + r;
            float v = oacc[dt][r] * invl[r];
            int col = h * HDIM + dt * 16 + fr;
            short hb = f2bf(v);
            short lb = f2bf(v - bf2f(hb));
            AoH[(size_t)i * DMODEL + col] = hb;
            AoL[(size_t)i * DMODEL + col] = lb;
        }
}

// ---------------------------------------------------------------------------
extern "C" void kernel_launch(void* const* d_in, const int* in_sizes, int n_in,
                              void* d_out, int out_size, void* d_ws, size_t ws_size,
                              hipStream_t stream)
{
    const float* x    = (const float*)d_in[0];
    const float* Wq   = (const float*)d_in[1];
    const float* Wk   = (const float*)d_in[2];
    const float* Wv   = (const float*)d_in[3];
    const float* Wo   = (const float*)d_in[4];
    const float* rsin = (const float*)d_in[5];
    const float* rcos = (const float*)d_in[6];
    const int*   swa  = (const int*)d_in[7];

    const int T = in_sizes[0] / DMODEL;   // 2048 (B=1)

    char* p = (char*)d_ws;
    short* WTh  = (short*)p; p += (size_t)3072 * 2048 * 2;   // [3072][2048] (Wq|Wk|Wv)^T hi
    short* WTl  = (short*)p; p += (size_t)3072 * 2048 * 2;
    short* WoTh = (short*)p; p += (size_t)2048 * 2048 * 2;
    short* WoTl = (short*)p; p += (size_t)2048 * 2048 * 2;
    short* Xh   = (short*)p; p += (size_t)T * DMODEL * 2;
    short* Xl   = (short*)p; p += (size_t)T * DMODEL * 2;
    short* Qbf  = (short*)p; p += (size_t)T * DMODEL * 2;
    short* Kbf  = (short*)p; p += (size_t)T * KVW * 2;
    short* Vbf  = (short*)p; p += (size_t)T * KVW * 2;
    short* Vt   = (short*)p; p += (size_t)T * KVW * 2;
    short* AoH  = Xh;   // alias: X dead after QKV gemm
    short* AoL  = Xl;

    // 1. split x into hi/lo bf16
    int n4 = T * DMODEL / 4;
    split_f32<<<(n4 + 255) / 256, 256, 0, stream>>>(x, Xh, Xl, n4);

    // 2. transpose+split weights into [N][K] bf16 hi/lo
    transpose_split_f32<<<dim3(2048 / 32, 2048 / 32), 256, 0, stream>>>(Wq, 2048, 2048, WTh, WTl, 2048);
    transpose_split_f32<<<dim3(512 / 32, 2048 / 32), 256, 0, stream>>>(Wk, 2048, 512, WTh + (size_t)2048 * 2048, WTl + (size_t)2048 * 2048, 2048);
    transpose_split_f32<<<dim3(512 / 32, 2048 / 32), 256, 0, stream>>>(Wv, 2048, 512, WTh + (size_t)2560 * 2048, WTl + (size_t)2560 * 2048, 2048);
    transpose_split_f32<<<dim3(2048 / 32, 2048 / 32), 256, 0, stream>>>(Wo, 2048, 2048, WoTh, WoTl, 2048);

    // 3. fused QKV projection (3-term bf16 MFMA) + RoPE epilogue
    gemm3<1><<<dim3(3072 / 128, T / 128), 256, 0, stream>>>(
        Xh, Xl, WTh, WTl, 2048, nullptr, 0, Qbf, Kbf, Vbf, rsin, rcos);

    // 4. V -> V^T [512][T]
    transpose_bf16<<<dim3(KVW / 32, T / 32), 256, 0, stream>>>(Vbf, T, KVW, Vt);

    // 5. attention
    attn_mfma<<<dim3(T / 64, NH), 256, 0, stream>>>(Qbf, Kbf, Vt, AoH, AoL, swa, T);

    // 6. output projection (3-term bf16 MFMA) -> fp32 out
    gemm3<0><<<dim3(2048 / 128, T / 128), 256, 0, stream>>>(
        AoH, AoL, WoTh, WoTl, 2048, (float*)d_out, 2048, nullptr, nullptr, nullptr, nullptr, nullptr);
}

// Round 9
// 322.160 us; speedup vs baseline: 3.6182x; 1.0998x over previous
//
#include <hip/hip_runtime.h>
#include <math.h>

#define DMODEL 2048
#define NH     32
#define NKV    8
#define HDIM   64
#define GROUP  4
#define KVW    (NKV * HDIM)   // 512

typedef short bf16x8 __attribute__((ext_vector_type(8)));
typedef float f32x4  __attribute__((ext_vector_type(4)));

__device__ __forceinline__ short f2bf(float f) {
    union { float f; unsigned u; } x; x.f = f;
    unsigned r = x.u + 0x7fffu + ((x.u >> 16) & 1u);   // RNE
    return (short)(r >> 16);
}
__device__ __forceinline__ float bf2f(short h) {
    union { unsigned u; float f; } x; x.u = ((unsigned)(unsigned short)h) << 16;
    return x.f;
}

typedef __attribute__((address_space(3))) void lds_void;
typedef const __attribute__((address_space(1))) void gbl_void;
__device__ __forceinline__ void gll16(const void* g, void* l) {
    __builtin_amdgcn_global_load_lds((gbl_void*)g, (lds_void*)l, 16, 0, 0);
}

// ---------------------------------------------------------------------------
// Elementwise fp32 -> (bf16 hi, bf16 lo) split
// ---------------------------------------------------------------------------
__global__ __launch_bounds__(256)
void split_f32(const float* __restrict__ in, short* __restrict__ oh,
               short* __restrict__ ol, int n4)
{
    int i = blockIdx.x * 256 + threadIdx.x;
    if (i >= n4) return;
    float4 v = ((const float4*)in)[i];
    short h0 = f2bf(v.x), h1 = f2bf(v.y), h2 = f2bf(v.z), h3 = f2bf(v.w);
    short l0 = f2bf(v.x - bf2f(h0)), l1 = f2bf(v.y - bf2f(h1));
    short l2 = f2bf(v.z - bf2f(h2)), l3 = f2bf(v.w - bf2f(h3));
    ((short4*)oh)[i] = make_short4(h0, h1, h2, h3);
    ((short4*)ol)[i] = make_short4(l0, l1, l2, l3);
}

// ---------------------------------------------------------------------------
// Transpose + split: W[K][N] fp32 -> WT_h/WT_l [N][K] bf16 (ldo = K)
// ---------------------------------------------------------------------------
__global__ __launch_bounds__(256)
void transpose_split_f32(const float* __restrict__ W, int K, int N,
                         short* __restrict__ oth, short* __restrict__ otl, int ldo)
{
    __shared__ float tile[32][33];
    const int bx = blockIdx.x, by = blockIdx.y;       // bx over N, by over K
    const int c = threadIdx.x & 31, r = threadIdx.x >> 5;
    #pragma unroll
    for (int it = 0; it < 4; ++it)
        tile[r + it * 8][c] = W[(size_t)(by * 32 + r + it * 8) * N + bx * 32 + c];
    __syncthreads();
    #pragma unroll
    for (int it = 0; it < 4; ++it) {
        int n = bx * 32 + r + it * 8;
        int k = by * 32 + c;
        float v = tile[c][r + it * 8];
        short h = f2bf(v), l = f2bf(v - bf2f(h));
        oth[(size_t)n * ldo + k] = h;
        otl[(size_t)n * ldo + k] = l;
    }
}

// ---------------------------------------------------------------------------
// bf16 transpose: in[R][C] -> out[C][R]   (for V -> V^T)
// ---------------------------------------------------------------------------
__global__ __launch_bounds__(256)
void transpose_bf16(const short* __restrict__ in, int R, int C,
                    short* __restrict__ out)
{
    __shared__ short tile[32][33];
    const int bx = blockIdx.x, by = blockIdx.y;       // bx over C, by over R
    const int c = threadIdx.x & 31, r = threadIdx.x >> 5;
    #pragma unroll
    for (int it = 0; it < 4; ++it)
        tile[r + it * 8][c] = in[(size_t)(by * 32 + r + it * 8) * C + bx * 32 + c];
    __syncthreads();
    #pragma unroll
    for (int it = 0; it < 4; ++it)
        out[(size_t)(bx * 32 + r + it * 8) * R + by * 32 + c] = tile[c][r + it * 8];
}

// ---------------------------------------------------------------------------
// 3-term bf16 MFMA GEMM with SPLIT-K=2: P[z][M][N] partial = A x B^T over
// K-half z. 128x128 tile, BK=32, 4 waves, single-buffered 32KB LDS
// (grid z=2 doubles occupancy: the TLP hides staging latency, m97-style).
// Swizzle f(row)=(row>>1)&3: 2-way max bank aliasing (free) vs old 4-way.
// ---------------------------------------------------------------------------
__global__ __launch_bounds__(256)
void gemm3s(const short* __restrict__ Ah, const short* __restrict__ Al,
            const short* __restrict__ Bh, const short* __restrict__ Bl,
            int K, int ldc, float* __restrict__ P)
{
    __shared__ __align__(16) short AhS[128 * 32];   // 32 KB total
    __shared__ __align__(16) short AlS[128 * 32];
    __shared__ __align__(16) short BhS[128 * 32];
    __shared__ __align__(16) short BlS[128 * 32];

    const int t = threadIdx.x, lane = t & 63, w = t >> 6;
    const int wr = (w >> 1) * 64, wc = (w & 1) * 64;
    const int m0 = blockIdx.y * 128, n0 = blockIdx.x * 128;
    const int kbase = blockIdx.z * (K >> 1);
    float* out = P + (size_t)blockIdx.z * ((size_t)gridDim.y * 128) * ldc;

    f32x4 zero = {0.f, 0.f, 0.f, 0.f};
    f32x4 acc[4][4];
    #pragma unroll
    for (int i = 0; i < 4; ++i)
        #pragma unroll
        for (int j = 0; j < 4; ++j) acc[i][j] = zero;

    // staging: chunk c = w*2+i covers rows c*16 .. c*16+15 (1024B each)
    const int sr0 = (w * 2 + 0) * 16 + (lane >> 2);
    const int sr1 = (w * 2 + 1) * 16 + (lane >> 2);
    const int sc0 = (((lane & 3) ^ ((sr0 >> 1) & 3)) * 8);   // 16B granule
    const int sc1 = (((lane & 3) ^ ((sr1 >> 1) & 3)) * 8);
    const size_t ga0 = (size_t)(m0 + sr0) * K + kbase + sc0;
    const size_t ga1 = (size_t)(m0 + sr1) * K + kbase + sc1;
    const size_t gb0 = (size_t)(n0 + sr0) * K + kbase + sc0;
    const size_t gb1 = (size_t)(n0 + sr1) * K + kbase + sc1;
    const int co0 = (w * 2 + 0) * 1024;
    const int co1 = (w * 2 + 1) * 1024;

    const int fr = lane & 15, fs = lane >> 4;

    const int nsteps = K >> 6;   // (K/2)/32
    for (int s = 0; s < nsteps; ++s) {
        const int k0 = s << 5;
        __syncthreads();                 // all waves done reading prev tile
        gll16(Ah + ga0 + k0, (char*)AhS + co0);
        gll16(Ah + ga1 + k0, (char*)AhS + co1);
        gll16(Al + ga0 + k0, (char*)AlS + co0);
        gll16(Al + ga1 + k0, (char*)AlS + co1);
        gll16(Bh + gb0 + k0, (char*)BhS + co0);
        gll16(Bh + gb1 + k0, (char*)BhS + co1);
        gll16(Bl + gb0 + k0, (char*)BlS + co0);
        gll16(Bl + gb1 + k0, (char*)BlS + co1);
        __syncthreads();                 // staged (implicit vmcnt(0) drain)

        bf16x8 fah[4], fal[4], fbh[4], fbl[4];
        #pragma unroll
        for (int i = 0; i < 4; ++i) {
            int ar = wr + i * 16 + fr;
            int aoff = ar * 64 + ((fs ^ ((ar >> 1) & 3)) << 4);
            fah[i] = *(const bf16x8*)((const char*)AhS + aoff);
            fal[i] = *(const bf16x8*)((const char*)AlS + aoff);
            int br = wc + i * 16 + fr;
            int boff = br * 64 + ((fs ^ ((br >> 1) & 3)) << 4);
            fbh[i] = *(const bf16x8*)((const char*)BhS + boff);
            fbl[i] = *(const bf16x8*)((const char*)BlS + boff);
        }
        #pragma unroll
        for (int i = 0; i < 4; ++i)
            #pragma unroll
            for (int j = 0; j < 4; ++j) {
                acc[i][j] = __builtin_amdgcn_mfma_f32_16x16x32_bf16(fah[i], fbh[j], acc[i][j], 0, 0, 0);
                acc[i][j] = __builtin_amdgcn_mfma_f32_16x16x32_bf16(fah[i], fbl[j], acc[i][j], 0, 0, 0);
                acc[i][j] = __builtin_amdgcn_mfma_f32_16x16x32_bf16(fal[i], fbh[j], acc[i][j], 0, 0, 0);
            }
    }

    const int g = lane >> 4;
    #pragma unroll
    for (int i = 0; i < 4; ++i)
        #pragma unroll
        for (int j = 0; j < 4; ++j)
            #pragma unroll
            for (int r = 0; r < 4; ++r) {
                int m = m0 + wr + i * 16 + g * 4 + r;
                int n = n0 + wc + j * 16 + fr;
                out[(size_t)m * ldc + n] = acc[i][j][r];
            }
}

// ---------------------------------------------------------------------------
// Split-K reduce for QKV + RoPE epilogue + bf16 store to Q/K/V buffers.
// Each thread: one row, 8 consecutive cols (4 RoPE pairs).
// ---------------------------------------------------------------------------
__global__ __launch_bounds__(256)
void reduce_qkv(const float* __restrict__ P,
                const float* __restrict__ rs, const float* __restrict__ rc,
                short* __restrict__ Qo, short* __restrict__ Ko,
                short* __restrict__ Vo)
{
    const int idx = blockIdx.x * 256 + threadIdx.x;   // T*3072/8 threads
    const int row = idx / 384;                        // 3072/8 = 384
    const int c8  = (idx - row * 384) * 8;
    const float* p0 = P + (size_t)row * 3072 + c8;
    const float* p1 = p0 + (size_t)2048 * 3072;
    float4 a0 = *(const float4*)p0,       a1 = *(const float4*)(p0 + 4);
    float4 b0 = *(const float4*)p1,       b1 = *(const float4*)(p1 + 4);
    float v[8] = {a0.x + b0.x, a0.y + b0.y, a0.z + b0.z, a0.w + b0.w,
                  a1.x + b1.x, a1.y + b1.y, a1.z + b1.z, a1.w + b1.w};
    if (c8 < 2560) {   // RoPE region (Q | K)
        int pib = (c8 & 63) >> 1;
        #pragma unroll
        for (int j = 0; j < 4; ++j) {
            float sn = rs[row * (HDIM / 2) + pib + j];
            float cs = rc[row * (HDIM / 2) + pib + j];
            float e = v[2 * j], o = v[2 * j + 1];
            v[2 * j]     = e * cs - o * sn;
            v[2 * j + 1] = e * sn + o * cs;
        }
    }
    short s[8];
    #pragma unroll
    for (int j = 0; j < 8; ++j) s[j] = f2bf(v[j]);
    short4 lo = make_short4(s[0], s[1], s[2], s[3]);
    short4 hi = make_short4(s[4], s[5], s[6], s[7]);
    if (c8 < 2048) {
        short* q = Qo + (size_t)row * DMODEL + c8;
        *(short4*)q = lo; *(short4*)(q + 4) = hi;
    } else if (c8 < 2560) {
        short* k = Ko + (size_t)row * KVW + (c8 - 2048);
        *(short4*)k = lo; *(short4*)(k + 4) = hi;
    } else {
        short* vv = Vo + (size_t)row * KVW + (c8 - 2560);
        *(short4*)vv = lo; *(short4*)(vv + 4) = hi;
    }
}

// ---------------------------------------------------------------------------
// Split-K reduce for output projection: d_out = P0 + P1 (fp32)
// ---------------------------------------------------------------------------
__global__ __launch_bounds__(256)
void reduce_out(const float* __restrict__ P, float* __restrict__ out)
{
    const int i = (blockIdx.x * 256 + threadIdx.x) * 8;   // 2048*2048 elems
    const float* p1 = P + (size_t)2048 * 2048;
    float4 a0 = *(const float4*)(P + i),  a1 = *(const float4*)(P + i + 4);
    float4 b0 = *(const float4*)(p1 + i), b1 = *(const float4*)(p1 + i + 4);
    float4 o0 = make_float4(a0.x + b0.x, a0.y + b0.y, a0.z + b0.z, a0.w + b0.w);
    float4 o1 = make_float4(a1.x + b1.x, a1.y + b1.y, a1.z + b1.z, a1.w + b1.w);
    *(float4*)(out + i) = o0;
    *(float4*)(out + i + 4) = o1;
}

// ---------------------------------------------------------------------------
// Flash attention, bf16 MFMA 16x16x32, causal + sliding window, GQA.
// Block = (64 q-rows, head); 4 waves x 16 q-rows; 32-key tiles.
// Double-buffered K/V staging, one barrier per tile; per-wave Ps (no barrier).
// s_setprio(1) around MFMA clusters (T5; attn blocks are independent).
// ---------------------------------------------------------------------------
__global__ __launch_bounds__(256)
void attn_mfma(const short* __restrict__ Qb, const short* __restrict__ Kb,
               const short* __restrict__ Vt, short* __restrict__ AoH,
               short* __restrict__ AoL, const int* __restrict__ swa_ptr, int T)
{
    __shared__ __align__(16) short Ks[2][32 * 64];   // 2 x 4 KB
    __shared__ __align__(16) short Vs[2][64 * 32];   // 2 x 4 KB
    __shared__ __align__(16) short Ps[4][16 * 32];   // 4 KB (per-wave)

    const int h = blockIdx.y, qt = blockIdx.x;
    const int q0 = qt * 64, hk = h >> 2;
    const int t = threadIdx.x, lane = t & 63, w = t >> 6;
    const int swa = *swa_ptr;
    const int fr = lane & 15, g = lane >> 4;
    const int qrow = q0 + w * 16;

    bf16x8 qf0, qf1;
    {
        const short* qp = Qb + (size_t)(qrow + fr) * DMODEL + h * HDIM + g * 8;
        qf0 = *(const bf16x8*)qp;
        qf1 = *(const bf16x8*)(qp + 32);
    }

    f32x4 zero = {0.f, 0.f, 0.f, 0.f};
    f32x4 oacc[4];
    #pragma unroll
    for (int dt = 0; dt < 4; ++dt) oacc[dt] = zero;
    float mreg[4] = {-INFINITY, -INFINITY, -INFINITY, -INFINITY};
    float lreg[4] = {0.f, 0.f, 0.f, 0.f};

    int kt_lo = 0;
    if (swa > 0) { int lo = q0 - swa; if (lo > 0) kt_lo = lo >> 5; }
    const int kt_hi = (q0 + 63) >> 5;

    const int krow = w * 8 + (lane >> 3);
    const int kcol = (((lane & 7) ^ (krow & 7)) * 8);
    const size_t kgbase = (size_t)krow * KVW + hk * HDIM + kcol;
    const int vrow = w * 16 + (lane >> 2);
    const int vcol = (((lane & 3) ^ (vrow & 3)) * 8);
    const size_t vgbase = (size_t)(hk * HDIM + vrow) * T + vcol;

    auto stage = [&](int kt, int p) {
        gll16(Kb + (size_t)(kt * 32) * KVW + kgbase, (char*)Ks[p] + w * 1024);
        gll16(Vt + vgbase + kt * 32, (char*)Vs[p] + w * 1024);
    };

    stage(kt_lo, 0);

    for (int kt = kt_lo; kt <= kt_hi; ++kt) {
        const int k0 = kt * 32;
        const int p = (kt - kt_lo) & 1;
        __syncthreads();                 // prefetch for kt landed
        if (kt + 1 <= kt_hi) stage(kt + 1, p ^ 1);

        // S = Q K^T
        f32x4 s0a = zero, s1a = zero;
        __builtin_amdgcn_s_setprio(1);
        #pragma unroll
        for (int ks = 0; ks < 2; ++ks) {
            int slot = g + ks * 4;
            int key0 = fr, key1 = 16 + fr;
            bf16x8 kf0 = *(const bf16x8*)((const char*)Ks[p] + key0 * 128 + ((slot ^ (key0 & 7)) << 4));
            bf16x8 kf1 = *(const bf16x8*)((const char*)Ks[p] + key1 * 128 + ((slot ^ (key1 & 7)) << 4));
            bf16x8 qf = ks ? qf1 : qf0;
            s0a = __builtin_amdgcn_mfma_f32_16x16x32_bf16(qf, kf0, s0a, 0, 0, 0);
            s1a = __builtin_amdgcn_mfma_f32_16x16x32_bf16(qf, kf1, s1a, 0, 0, 0);
        }
        __builtin_amdgcn_s_setprio(0);

        const bool full = (k0 + 31 <= qrow) && (swa <= 0 || (qrow + 15 - k0) <= swa);

        float alpha[4], p0v[4], p1v[4];
        #pragma unroll
        for (int r = 0; r < 4; ++r) {
            float s0, s1;
            if (full) {
                s0 = s0a[r] * 0.125f;
                s1 = s1a[r] * 0.125f;
            } else {
                int i = qrow + g * 4 + r;
                int j0 = k0 + fr, j1 = k0 + 16 + fr;
                int d0 = i - j0, d1 = i - j1;
                s0 = (d0 >= 0 && (swa <= 0 || d0 <= swa)) ? s0a[r] * 0.125f : -INFINITY;
                s1 = (d1 >= 0 && (swa <= 0 || d1 <= swa)) ? s1a[r] * 0.125f : -INFINITY;
            }
            float rm = fmaxf(s0, s1);
            rm = fmaxf(rm, __shfl_xor(rm, 1));
            rm = fmaxf(rm, __shfl_xor(rm, 2));
            rm = fmaxf(rm, __shfl_xor(rm, 4));
            rm = fmaxf(rm, __shfl_xor(rm, 8));
            float mo = mreg[r];
            float mn = fmaxf(mo, rm);
            float a, p0, p1;
            if (mn == -INFINITY) { a = 1.f; p0 = 0.f; p1 = 0.f; }
            else {
                a  = __expf(mo - mn);
                p0 = __expf(s0 - mn);
                p1 = __expf(s1 - mn);
            }
            float rsum = p0 + p1;
            rsum += __shfl_xor(rsum, 1);
            rsum += __shfl_xor(rsum, 2);
            rsum += __shfl_xor(rsum, 4);
            rsum += __shfl_xor(rsum, 8);
            mreg[r] = mn;
            lreg[r] = lreg[r] * a + rsum;
            alpha[r] = a;
            p0v[r] = p0;
            p1v[r] = p1;
        }

        #pragma unroll
        for (int r = 0; r < 4; ++r) {
            int row = g * 4 + r;
            int c0 = fr, c1 = 16 + fr;
            *(short*)((char*)Ps[w] + row * 64 + (((c0 >> 3) ^ (row & 3)) << 4) + ((c0 & 7) << 1)) = f2bf(p0v[r]);
            *(short*)((char*)Ps[w] + row * 64 + (((c1 >> 3) ^ (row & 3)) << 4) + ((c1 & 7) << 1)) = f2bf(p1v[r]);
        }
        // Ps[w] is wave-private: same-wave RAW ordered by lgkmcnt

        #pragma unroll
        for (int dt = 0; dt < 4; ++dt)
            #pragma unroll
            for (int r = 0; r < 4; ++r) oacc[dt][r] = oacc[dt][r] * alpha[r];

        {
            int prow = fr;
            bf16x8 pf = *(const bf16x8*)((const char*)Ps[w] + prow * 64 + ((g ^ (prow & 3)) << 4));
            __builtin_amdgcn_s_setprio(1);
            #pragma unroll
            for (int dt = 0; dt < 4; ++dt) {
                int d = dt * 16 + fr;
                bf16x8 vf = *(const bf16x8*)((const char*)Vs[p] + d * 64 + ((g ^ (d & 3)) << 4));
                oacc[dt] = __builtin_amdgcn_mfma_f32_16x16x32_bf16(pf, vf, oacc[dt], 0, 0, 0);
            }
            __builtin_amdgcn_s_setprio(0);
        }
    }

    float invl[4];
    #pragma unroll
    for (int r = 0; r < 4; ++r) invl[r] = 1.0f / lreg[r];
    #pragma unroll
    for (int dt = 0; dt < 4; ++dt)
        #pragma unroll
        for (int r = 0; r < 4; ++r) {
            int i = qrow + g * 4 + r;
            float v = oacc[dt][r] * invl[r];
            int col = h * HDIM + dt * 16 + fr;
            short hb = f2bf(v);
            short lb = f2bf(v - bf2f(hb));
            AoH[(size_t)i * DMODEL + col] = hb;
            AoL[(size_t)i * DMODEL + col] = lb;
        }
}

// ---------------------------------------------------------------------------
extern "C" void kernel_launch(void* const* d_in, const int* in_sizes, int n_in,
                              void* d_out, int out_size, void* d_ws, size_t ws_size,
                              hipStream_t stream)
{
    const float* x    = (const float*)d_in[0];
    const float* Wq   = (const float*)d_in[1];
    const float* Wk   = (const float*)d_in[2];
    const float* Wv   = (const float*)d_in[3];
    const float* Wo   = (const float*)d_in[4];
    const float* rsin = (const float*)d_in[5];
    const float* rcos = (const float*)d_in[6];
    const int*   swa  = (const int*)d_in[7];

    const int T = in_sizes[0] / DMODEL;   // 2048 (B=1)

    char* p = (char*)d_ws;
    short* WTh  = (short*)p; p += (size_t)3072 * 2048 * 2;   // (Wq|Wk|Wv)^T hi
    short* WTl  = (short*)p; p += (size_t)3072 * 2048 * 2;
    short* WoTh = (short*)p; p += (size_t)2048 * 2048 * 2;
    short* WoTl = (short*)p; p += (size_t)2048 * 2048 * 2;
    short* Xh   = (short*)p; p += (size_t)T * DMODEL * 2;
    short* Xl   = (short*)p; p += (size_t)T * DMODEL * 2;
    short* Qbf  = (short*)p; p += (size_t)T * DMODEL * 2;
    short* Kbf  = (short*)p; p += (size_t)T * KVW * 2;
    short* Vbf  = (short*)p; p += (size_t)T * KVW * 2;
    short* Vt   = (short*)p; p += (size_t)T * KVW * 2;
    float* Part = (float*)p; p += (size_t)2 * T * 3072 * 4;  // split-K partials (50MB)
    short* AoH  = Xh;   // alias: X dead after QKV gemm
    short* AoL  = Xl;

    // 1. split x into hi/lo bf16
    int n4 = T * DMODEL / 4;
    split_f32<<<(n4 + 255) / 256, 256, 0, stream>>>(x, Xh, Xl, n4);

    // 2. transpose+split weights into [N][K] bf16 hi/lo
    transpose_split_f32<<<dim3(2048 / 32, 2048 / 32), 256, 0, stream>>>(Wq, 2048, 2048, WTh, WTl, 2048);
    transpose_split_f32<<<dim3(512 / 32, 2048 / 32), 256, 0, stream>>>(Wk, 2048, 512, WTh + (size_t)2048 * 2048, WTl + (size_t)2048 * 2048, 2048);
    transpose_split_f32<<<dim3(512 / 32, 2048 / 32), 256, 0, stream>>>(Wv, 2048, 512, WTh + (size_t)2560 * 2048, WTl + (size_t)2560 * 2048, 2048);
    transpose_split_f32<<<dim3(2048 / 32, 2048 / 32), 256, 0, stream>>>(Wo, 2048, 2048, WoTh, WoTl, 2048);

    // 3. QKV projection, split-K=2 (768 blocks = 3/CU) -> fp32 partials
    gemm3s<<<dim3(3072 / 128, T / 128, 2), 256, 0, stream>>>(
        Xh, Xl, WTh, WTl, 2048, 3072, Part);
    // 3b. reduce + RoPE + bf16 -> Q/K/V
    reduce_qkv<<<T * 3072 / 8 / 256, 256, 0, stream>>>(Part, rsin, rcos, Qbf, Kbf, Vbf);

    // 4. V -> V^T [512][T]
    transpose_bf16<<<dim3(KVW / 32, T / 32), 256, 0, stream>>>(Vbf, T, KVW, Vt);

    // 5. attention
    attn_mfma<<<dim3(T / 64, NH), 256, 0, stream>>>(Qbf, Kbf, Vt, AoH, AoL, swa, T);

    // 6. output projection, split-K=2 (512 blocks = 2/CU) -> partials
    gemm3s<<<dim3(2048 / 128, T / 128, 2), 256, 0, stream>>>(
        AoH, AoL, WoTh, WoTl, 2048, 2048, Part);
    // 6b. reduce -> fp32 out
    reduce_out<<<T * 2048 / 8 / 256, 256, 0, stream>>>(Part, (float*)d_out);
}

// Round 11
// 303.257 us; speedup vs baseline: 3.8437x; 1.0623x over previous
//
#include <hip/hip_runtime.h>
#include <math.h>

#define DMODEL 2048
#define NH     32
#define NKV    8
#define HDIM   64
#define GROUP  4
#define KVW    (NKV * HDIM)   // 512

typedef short bf16x8 __attribute__((ext_vector_type(8)));
typedef float f32x4  __attribute__((ext_vector_type(4)));

__device__ __forceinline__ short f2bf(float f) {
    union { float f; unsigned u; } x; x.f = f;
    unsigned r = x.u + 0x7fffu + ((x.u >> 16) & 1u);   // RNE
    return (short)(r >> 16);
}
__device__ __forceinline__ float bf2f(short h) {
    union { unsigned u; float f; } x; x.u = ((unsigned)(unsigned short)h) << 16;
    return x.f;
}

typedef __attribute__((address_space(3))) void lds_void;
typedef const __attribute__((address_space(1))) void gbl_void;
__device__ __forceinline__ void gll16(const void* g, void* l) {
    __builtin_amdgcn_global_load_lds((gbl_void*)g, (lds_void*)l, 16, 0, 0);
}

// ---------------------------------------------------------------------------
// Elementwise fp32 -> (bf16 hi, bf16 lo) split
// ---------------------------------------------------------------------------
__global__ __launch_bounds__(256)
void split_f32(const float* __restrict__ in, short* __restrict__ oh,
               short* __restrict__ ol, int n4)
{
    int i = blockIdx.x * 256 + threadIdx.x;
    if (i >= n4) return;
    float4 v = ((const float4*)in)[i];
    short h0 = f2bf(v.x), h1 = f2bf(v.y), h2 = f2bf(v.z), h3 = f2bf(v.w);
    short l0 = f2bf(v.x - bf2f(h0)), l1 = f2bf(v.y - bf2f(h1));
    short l2 = f2bf(v.z - bf2f(h2)), l3 = f2bf(v.w - bf2f(h3));
    ((short4*)oh)[i] = make_short4(h0, h1, h2, h3);
    ((short4*)ol)[i] = make_short4(l0, l1, l2, l3);
}

// ---------------------------------------------------------------------------
// Transpose + split: W[K][N] fp32 -> WT_h/WT_l [N][K] bf16 (ldo = K)
// ---------------------------------------------------------------------------
__global__ __launch_bounds__(256)
void transpose_split_f32(const float* __restrict__ W, int K, int N,
                         short* __restrict__ oth, short* __restrict__ otl, int ldo)
{
    __shared__ float tile[32][33];
    const int bx = blockIdx.x, by = blockIdx.y;       // bx over N, by over K
    const int c = threadIdx.x & 31, r = threadIdx.x >> 5;
    #pragma unroll
    for (int it = 0; it < 4; ++it)
        tile[r + it * 8][c] = W[(size_t)(by * 32 + r + it * 8) * N + bx * 32 + c];
    __syncthreads();
    #pragma unroll
    for (int it = 0; it < 4; ++it) {
        int n = bx * 32 + r + it * 8;
        int k = by * 32 + c;
        float v = tile[c][r + it * 8];
        short h = f2bf(v), l = f2bf(v - bf2f(h));
        oth[(size_t)n * ldo + k] = h;
        otl[(size_t)n * ldo + k] = l;
    }
}

// ---------------------------------------------------------------------------
// bf16 transpose: in[R][C] -> out[C][R]   (for V -> V^T)
// ---------------------------------------------------------------------------
__global__ __launch_bounds__(256)
void transpose_bf16(const short* __restrict__ in, int R, int C,
                    short* __restrict__ out)
{
    __shared__ short tile[32][33];
    const int bx = blockIdx.x, by = blockIdx.y;       // bx over C, by over R
    const int c = threadIdx.x & 31, r = threadIdx.x >> 5;
    #pragma unroll
    for (int it = 0; it < 4; ++it)
        tile[r + it * 8][c] = in[(size_t)(by * 32 + r + it * 8) * C + bx * 32 + c];
    __syncthreads();
    #pragma unroll
    for (int it = 0; it < 4; ++it)
        out[(size_t)(bx * 32 + r + it * 8) * R + by * 32 + c] = tile[c][r + it * 8];
}

// ---------------------------------------------------------------------------
// 3-term bf16 MFMA GEMM with SPLIT-K=2 (unchanged from round 9: at the
// 128x128/2-barrier structural ceiling, ~980 TF effective, 0 bank conflicts)
// ---------------------------------------------------------------------------
__global__ __launch_bounds__(256)
void gemm3s(const short* __restrict__ Ah, const short* __restrict__ Al,
            const short* __restrict__ Bh, const short* __restrict__ Bl,
            int K, int ldc, float* __restrict__ P)
{
    __shared__ __align__(16) short AhS[128 * 32];   // 32 KB total
    __shared__ __align__(16) short AlS[128 * 32];
    __shared__ __align__(16) short BhS[128 * 32];
    __shared__ __align__(16) short BlS[128 * 32];

    const int t = threadIdx.x, lane = t & 63, w = t >> 6;
    const int wr = (w >> 1) * 64, wc = (w & 1) * 64;
    const int m0 = blockIdx.y * 128, n0 = blockIdx.x * 128;
    const int kbase = blockIdx.z * (K >> 1);
    float* out = P + (size_t)blockIdx.z * ((size_t)gridDim.y * 128) * ldc;

    f32x4 zero = {0.f, 0.f, 0.f, 0.f};
    f32x4 acc[4][4];
    #pragma unroll
    for (int i = 0; i < 4; ++i)
        #pragma unroll
        for (int j = 0; j < 4; ++j) acc[i][j] = zero;

    const int sr0 = (w * 2 + 0) * 16 + (lane >> 2);
    const int sr1 = (w * 2 + 1) * 16 + (lane >> 2);
    const int sc0 = (((lane & 3) ^ ((sr0 >> 1) & 3)) * 8);   // 16B granule
    const int sc1 = (((lane & 3) ^ ((sr1 >> 1) & 3)) * 8);
    const size_t ga0 = (size_t)(m0 + sr0) * K + kbase + sc0;
    const size_t ga1 = (size_t)(m0 + sr1) * K + kbase + sc1;
    const size_t gb0 = (size_t)(n0 + sr0) * K + kbase + sc0;
    const size_t gb1 = (size_t)(n0 + sr1) * K + kbase + sc1;
    const int co0 = (w * 2 + 0) * 1024;
    const int co1 = (w * 2 + 1) * 1024;

    const int fr = lane & 15, fs = lane >> 4;

    const int nsteps = K >> 6;   // (K/2)/32
    for (int s = 0; s < nsteps; ++s) {
        const int k0 = s << 5;
        __syncthreads();
        gll16(Ah + ga0 + k0, (char*)AhS + co0);
        gll16(Ah + ga1 + k0, (char*)AhS + co1);
        gll16(Al + ga0 + k0, (char*)AlS + co0);
        gll16(Al + ga1 + k0, (char*)AlS + co1);
        gll16(Bh + gb0 + k0, (char*)BhS + co0);
        gll16(Bh + gb1 + k0, (char*)BhS + co1);
        gll16(Bl + gb0 + k0, (char*)BlS + co0);
        gll16(Bl + gb1 + k0, (char*)BlS + co1);
        __syncthreads();

        bf16x8 fah[4], fal[4], fbh[4], fbl[4];
        #pragma unroll
        for (int i = 0; i < 4; ++i) {
            int ar = wr + i * 16 + fr;
            int aoff = ar * 64 + ((fs ^ ((ar >> 1) & 3)) << 4);
            fah[i] = *(const bf16x8*)((const char*)AhS + aoff);
            fal[i] = *(const bf16x8*)((const char*)AlS + aoff);
            int br = wc + i * 16 + fr;
            int boff = br * 64 + ((fs ^ ((br >> 1) & 3)) << 4);
            fbh[i] = *(const bf16x8*)((const char*)BhS + boff);
            fbl[i] = *(const bf16x8*)((const char*)BlS + boff);
        }
        #pragma unroll
        for (int i = 0; i < 4; ++i)
            #pragma unroll
            for (int j = 0; j < 4; ++j) {
                acc[i][j] = __builtin_amdgcn_mfma_f32_16x16x32_bf16(fah[i], fbh[j], acc[i][j], 0, 0, 0);
                acc[i][j] = __builtin_amdgcn_mfma_f32_16x16x32_bf16(fah[i], fbl[j], acc[i][j], 0, 0, 0);
                acc[i][j] = __builtin_amdgcn_mfma_f32_16x16x32_bf16(fal[i], fbh[j], acc[i][j], 0, 0, 0);
            }
    }

    const int g = lane >> 4;
    #pragma unroll
    for (int i = 0; i < 4; ++i)
        #pragma unroll
        for (int j = 0; j < 4; ++j)
            #pragma unroll
            for (int r = 0; r < 4; ++r) {
                int m = m0 + wr + i * 16 + g * 4 + r;
                int n = n0 + wc + j * 16 + fr;
                out[(size_t)m * ldc + n] = acc[i][j][r];
            }
}

// ---------------------------------------------------------------------------
// Split-K reduce for QKV + RoPE epilogue + bf16 store to Q/K/V buffers.
// ---------------------------------------------------------------------------
__global__ __launch_bounds__(256)
void reduce_qkv(const float* __restrict__ P,
                const float* __restrict__ rs, const float* __restrict__ rc,
                short* __restrict__ Qo, short* __restrict__ Ko,
                short* __restrict__ Vo)
{
    const int idx = blockIdx.x * 256 + threadIdx.x;   // T*3072/8 threads
    const int row = idx / 384;                        // 3072/8 = 384
    const int c8  = (idx - row * 384) * 8;
    const float* p0 = P + (size_t)row * 3072 + c8;
    const float* p1 = p0 + (size_t)2048 * 3072;
    float4 a0 = *(const float4*)p0,       a1 = *(const float4*)(p0 + 4);
    float4 b0 = *(const float4*)p1,       b1 = *(const float4*)(p1 + 4);
    float v[8] = {a0.x + b0.x, a0.y + b0.y, a0.z + b0.z, a0.w + b0.w,
                  a1.x + b1.x, a1.y + b1.y, a1.z + b1.z, a1.w + b1.w};
    if (c8 < 2560) {   // RoPE region (Q | K)
        int pib = (c8 & 63) >> 1;
        #pragma unroll
        for (int j = 0; j < 4; ++j) {
            float sn = rs[row * (HDIM / 2) + pib + j];
            float cs = rc[row * (HDIM / 2) + pib + j];
            float e = v[2 * j], o = v[2 * j + 1];
            v[2 * j]     = e * cs - o * sn;
            v[2 * j + 1] = e * sn + o * cs;
        }
    }
    short s[8];
    #pragma unroll
    for (int j = 0; j < 8; ++j) s[j] = f2bf(v[j]);
    short4 lo = make_short4(s[0], s[1], s[2], s[3]);
    short4 hi = make_short4(s[4], s[5], s[6], s[7]);
    if (c8 < 2048) {
        short* q = Qo + (size_t)row * DMODEL + c8;
        *(short4*)q = lo; *(short4*)(q + 4) = hi;
    } else if (c8 < 2560) {
        short* k = Ko + (size_t)row * KVW + (c8 - 2048);
        *(short4*)k = lo; *(short4*)(k + 4) = hi;
    } else {
        short* vv = Vo + (size_t)row * KVW + (c8 - 2560);
        *(short4*)vv = lo; *(short4*)(vv + 4) = hi;
    }
}

// ---------------------------------------------------------------------------
// Split-K reduce for output projection: d_out = P0 + P1 (fp32)
// ---------------------------------------------------------------------------
__global__ __launch_bounds__(256)
void reduce_out(const float* __restrict__ P, float* __restrict__ out)
{
    const int i = (blockIdx.x * 256 + threadIdx.x) * 8;   // 2048*2048 elems
    const float* p1 = P + (size_t)2048 * 2048;
    float4 a0 = *(const float4*)(P + i),  a1 = *(const float4*)(P + i + 4);
    float4 b0 = *(const float4*)(p1 + i), b1 = *(const float4*)(p1 + i + 4);
    float4 o0 = make_float4(a0.x + b0.x, a0.y + b0.y, a0.z + b0.z, a0.w + b0.w);
    float4 o1 = make_float4(a1.x + b1.x, a1.y + b1.y, a1.z + b1.z, a1.w + b1.w);
    *(float4*)(out + i) = o0;
    *(float4*)(out + i + 4) = o1;
}

// ---------------------------------------------------------------------------
// Flash attention, bf16 MFMA, causal + SWA, GQA.
// KVBLK = 64: one softmax pass / rescale / barrier per 64 keys (halved
// per-key softmax+shfl+barrier cost vs KVBLK=32; MFMA per key unchanged).
// Block = (64 q-rows, head); 4 waves x 16 q-rows; ~9 tile iterations.
// K,V^T 128B rows, &7 XOR swizzle both sides; Ps per-wave (no barrier).
// ---------------------------------------------------------------------------
__global__ __launch_bounds__(256)
void attn_mfma(const short* __restrict__ Qb, const short* __restrict__ Kb,
               const short* __restrict__ Vt, short* __restrict__ AoH,
               short* __restrict__ AoL, const int* __restrict__ swa_ptr, int T)
{
    __shared__ __align__(16) short Ks[2][64 * 64];   // 2 x 8 KB
    __shared__ __align__(16) short Vs[2][64 * 64];   // 2 x 8 KB
    __shared__ __align__(16) short Ps[4][16 * 64];   // 8 KB (per-wave 2KB)

    const int h = blockIdx.y, qt = blockIdx.x;
    const int q0 = qt * 64, hk = h >> 2;
    const int t = threadIdx.x, lane = t & 63, w = t >> 6;
    const int swa = *swa_ptr;
    const int fr = lane & 15, g = lane >> 4;
    const int qrow = q0 + w * 16;

    bf16x8 qf0, qf1;
    {
        const short* qp = Qb + (size_t)(qrow + fr) * DMODEL + h * HDIM + g * 8;
        qf0 = *(const bf16x8*)qp;
        qf1 = *(const bf16x8*)(qp + 32);
    }

    f32x4 zero = {0.f, 0.f, 0.f, 0.f};
    f32x4 oacc[4];
    #pragma unroll
    for (int dt = 0; dt < 4; ++dt) oacc[dt] = zero;
    float mreg[4] = {-INFINITY, -INFINITY, -INFINITY, -INFINITY};
    float lreg[4] = {0.f, 0.f, 0.f, 0.f};

    int kt_lo = 0;
    if (swa > 0) { int lo = q0 - swa; if (lo > 0) kt_lo = lo >> 6; }
    const int kt_hi = (q0 + 63) >> 6;

    // staging geometry: tile rows srow (+8 for 2nd chunk), 16B col granules
    const int srow = w * 16 + (lane >> 3);                  // 0..63
    const int scol = (((lane & 7) ^ (srow & 7)) * 8);       // pre-swizzled col
    const size_t kg0 = (size_t)srow * KVW + hk * HDIM + scol;
    const size_t kg1 = (size_t)(srow + 8) * KVW + hk * HDIM + scol;
    const size_t vg0 = (size_t)(hk * HDIM + srow) * T + scol;
    const size_t vg1 = (size_t)(hk * HDIM + srow + 8) * T + scol;

    auto stage = [&](int kt, int p) {
        const size_t koff = (size_t)(kt * 64) * KVW;
        gll16(Kb + koff + kg0, (char*)Ks[p] + w * 2048);
        gll16(Kb + koff + kg1, (char*)Ks[p] + w * 2048 + 1024);
        gll16(Vt + vg0 + kt * 64, (char*)Vs[p] + w * 2048);
        gll16(Vt + vg1 + kt * 64, (char*)Vs[p] + w * 2048 + 1024);
    };

    stage(kt_lo, 0);

    for (int kt = kt_lo; kt <= kt_hi; ++kt) {
        const int k0 = kt * 64;
        const int p = (kt - kt_lo) & 1;
        __syncthreads();                 // prefetch for kt landed
        if (kt + 1 <= kt_hi) stage(kt + 1, p ^ 1);

        // S = Q K^T over 4 16-key chunks x 2 d-halves
        f32x4 s[4];
        s[0] = zero; s[1] = zero; s[2] = zero; s[3] = zero;
        __builtin_amdgcn_s_setprio(1);
        #pragma unroll
        for (int c = 0; c < 4; ++c) {
            int key = c * 16 + fr;
            #pragma unroll
            for (int ks = 0; ks < 2; ++ks) {
                int slot = ks * 4 + g;
                bf16x8 kf = *(const bf16x8*)((const char*)Ks[p] + key * 128 + ((slot ^ (key & 7)) << 4));
                s[c] = __builtin_amdgcn_mfma_f32_16x16x32_bf16(ks ? qf1 : qf0, kf, s[c], 0, 0, 0);
            }
        }
        __builtin_amdgcn_s_setprio(0);

        const bool full = (k0 + 63 <= qrow) && (swa <= 0 || (qrow + 15 - k0) <= swa);

        // one softmax pass over all 64 keys; P written inline (per-wave LDS)
        float alpha[4];
        #pragma unroll
        for (int r = 0; r < 4; ++r) {
            int i = qrow + g * 4 + r;
            float sv[4];
            if (full) {
                #pragma unroll
                for (int c = 0; c < 4; ++c) sv[c] = s[c][r] * 0.125f;
            } else {
                #pragma unroll
                for (int c = 0; c < 4; ++c) {
                    int j = k0 + c * 16 + fr;
                    int dl = i - j;
                    sv[c] = (dl >= 0 && (swa <= 0 || dl <= swa)) ? s[c][r] * 0.125f : -INFINITY;
                }
            }
            float rm = fmaxf(fmaxf(sv[0], sv[1]), fmaxf(sv[2], sv[3]));
            rm = fmaxf(rm, __shfl_xor(rm, 1));
            rm = fmaxf(rm, __shfl_xor(rm, 2));
            rm = fmaxf(rm, __shfl_xor(rm, 4));
            rm = fmaxf(rm, __shfl_xor(rm, 8));
            float mo = mreg[r];
            float mn = fmaxf(mo, rm);
            float a, pe[4];
            if (mn == -INFINITY) {
                a = 1.f; pe[0] = pe[1] = pe[2] = pe[3] = 0.f;
            } else {
                a = __expf(mo - mn);
                #pragma unroll
                for (int c = 0; c < 4; ++c) pe[c] = __expf(sv[c] - mn);
            }
            float rsum = (pe[0] + pe[1]) + (pe[2] + pe[3]);
            rsum += __shfl_xor(rsum, 1);
            rsum += __shfl_xor(rsum, 2);
            rsum += __shfl_xor(rsum, 4);
            rsum += __shfl_xor(rsum, 8);
            mreg[r] = mn;
            lreg[r] = lreg[r] * a + rsum;
            alpha[r] = a;
            // write P row (q-row), keys c*16+fr, &7 swizzle (row stride 128B)
            int row = g * 4 + r;
            #pragma unroll
            for (int c = 0; c < 4; ++c) {
                int j = c * 16 + fr;
                *(short*)((char*)Ps[w] + row * 128 + ((((j >> 3) ^ (row & 7)) << 4)) + ((j & 7) << 1)) = f2bf(pe[c]);
            }
        }
        // Ps[w] wave-private: same-wave RAW ordered by lgkmcnt

        // rescale O, then PV over 2 32-key k-steps
        #pragma unroll
        for (int dt = 0; dt < 4; ++dt)
            #pragma unroll
            for (int r = 0; r < 4; ++r) oacc[dt][r] = oacc[dt][r] * alpha[r];

        __builtin_amdgcn_s_setprio(1);
        #pragma unroll
        for (int c2 = 0; c2 < 2; ++c2) {
            bf16x8 pf = *(const bf16x8*)((const char*)Ps[w] + fr * 128 + (((c2 * 4 + g) ^ (fr & 7)) << 4));
            #pragma unroll
            for (int dt = 0; dt < 4; ++dt) {
                int d = dt * 16 + fr;
                bf16x8 vf = *(const bf16x8*)((const char*)Vs[p] + d * 128 + (((c2 * 4 + g) ^ (d & 7)) << 4));
                oacc[dt] = __builtin_amdgcn_mfma_f32_16x16x32_bf16(pf, vf, oacc[dt], 0, 0, 0);
            }
        }
        __builtin_amdgcn_s_setprio(0);
    }

    float invl[4];
    #pragma unroll
    for (int r = 0; r < 4; ++r) invl[r] = 1.0f / lreg[r];
    #pragma unroll
    for (int dt = 0; dt < 4; ++dt)
        #pragma unroll
        for (int r = 0; r < 4; ++r) {
            int i = qrow + g * 4 + r;
            float v = oacc[dt][r] * invl[r];
            int col = h * HDIM + dt * 16 + fr;
            short hb = f2bf(v);
            short lb = f2bf(v - bf2f(hb));
            AoH[(size_t)i * DMODEL + col] = hb;
            AoL[(size_t)i * DMODEL + col] = lb;
        }
}

// ---------------------------------------------------------------------------
extern "C" void kernel_launch(void* const* d_in, const int* in_sizes, int n_in,
                              void* d_out, int out_size, void* d_ws, size_t ws_size,
                              hipStream_t stream)
{
    const float* x    = (const float*)d_in[0];
    const float* Wq   = (const float*)d_in[1];
    const float* Wk   = (const float*)d_in[2];
    const float* Wv   = (const float*)d_in[3];
    const float* Wo   = (const float*)d_in[4];
    const float* rsin = (const float*)d_in[5];
    const float* rcos = (const float*)d_in[6];
    const int*   swa  = (const int*)d_in[7];

    const int T = in_sizes[0] / DMODEL;   // 2048 (B=1)

    char* p = (char*)d_ws;
    short* WTh  = (short*)p; p += (size_t)3072 * 2048 * 2;   // (Wq|Wk|Wv)^T hi
    short* WTl  = (short*)p; p += (size_t)3072 * 2048 * 2;
    short* WoTh = (short*)p; p += (size_t)2048 * 2048 * 2;
    short* WoTl = (short*)p; p += (size_t)2048 * 2048 * 2;
    short* Xh   = (short*)p; p += (size_t)T * DMODEL * 2;
    short* Xl   = (short*)p; p += (size_t)T * DMODEL * 2;
    short* Qbf  = (short*)p; p += (size_t)T * DMODEL * 2;
    short* Kbf  = (short*)p; p += (size_t)T * KVW * 2;
    short* Vbf  = (short*)p; p += (size_t)T * KVW * 2;
    short* Vt   = (short*)p; p += (size_t)T * KVW * 2;
    float* Part = (float*)p; p += (size_t)2 * T * 3072 * 4;  // split-K partials
    short* AoH  = Xh;   // alias: X dead after QKV gemm
    short* AoL  = Xl;

    // 1. split x into hi/lo bf16
    int n4 = T * DMODEL / 4;
    split_f32<<<(n4 + 255) / 256, 256, 0, stream>>>(x, Xh, Xl, n4);

    // 2. transpose+split weights into [N][K] bf16 hi/lo
    transpose_split_f32<<<dim3(2048 / 32, 2048 / 32), 256, 0, stream>>>(Wq, 2048, 2048, WTh, WTl, 2048);
    transpose_split_f32<<<dim3(512 / 32, 2048 / 32), 256, 0, stream>>>(Wk, 2048, 512, WTh + (size_t)2048 * 2048, WTl + (size_t)2048 * 2048, 2048);
    transpose_split_f32<<<dim3(512 / 32, 2048 / 32), 256, 0, stream>>>(Wv, 2048, 512, WTh + (size_t)2560 * 2048, WTl + (size_t)2560 * 2048, 2048);
    transpose_split_f32<<<dim3(2048 / 32, 2048 / 32), 256, 0, stream>>>(Wo, 2048, 2048, WoTh, WoTl, 2048);

    // 3. QKV projection, split-K=2 (768 blocks = 3/CU) -> fp32 partials
    gemm3s<<<dim3(3072 / 128, T / 128, 2), 256, 0, stream>>>(
        Xh, Xl, WTh, WTl, 2048, 3072, Part);
    // 3b. reduce + RoPE + bf16 -> Q/K/V
    reduce_qkv<<<T * 3072 / 8 / 256, 256, 0, stream>>>(Part, rsin, rcos, Qbf, Kbf, Vbf);

    // 4. V -> V^T [512][T]
    transpose_bf16<<<dim3(KVW / 32, T / 32), 256, 0, stream>>>(Vbf, T, KVW, Vt);

    // 5. attention (KVBLK=64)
    attn_mfma<<<dim3(T / 64, NH), 256, 0, stream>>>(Qbf, Kbf, Vt, AoH, AoL, swa, T);

    // 6. output projection, split-K=2 (512 blocks = 2/CU) -> partials
    gemm3s<<<dim3(2048 / 128, T / 128, 2), 256, 0, stream>>>(
        AoH, AoL, WoTh, WoTl, 2048, 2048, Part);
    // 6b. reduce -> fp32 out
    reduce_out<<<T * 2048 / 8 / 256, 256, 0, stream>>>(Part, (float*)d_out);
}

// Round 12
// 297.814 us; speedup vs baseline: 3.9139x; 1.0183x over previous
//
#include <hip/hip_runtime.h>
#include <math.h>

#define DMODEL 2048
#define NH     32
#define NKV    8
#define HDIM   64
#define GROUP  4
#define KVW    (NKV * HDIM)   // 512

typedef short bf16x8 __attribute__((ext_vector_type(8)));
typedef float f32x4  __attribute__((ext_vector_type(4)));

__device__ __forceinline__ short f2bf(float f) {
    union { float f; unsigned u; } x; x.f = f;
    unsigned r = x.u + 0x7fffu + ((x.u >> 16) & 1u);   // RNE
    return (short)(r >> 16);
}
__device__ __forceinline__ float bf2f(short h) {
    union { unsigned u; float f; } x; x.u = ((unsigned)(unsigned short)h) << 16;
    return x.f;
}

typedef __attribute__((address_space(3))) void lds_void;
typedef const __attribute__((address_space(1))) void gbl_void;
__device__ __forceinline__ void gll16(const void* g, void* l) {
    __builtin_amdgcn_global_load_lds((gbl_void*)g, (lds_void*)l, 16, 0, 0);
}

// ---------------------------------------------------------------------------
// Elementwise fp32 -> (bf16 hi, bf16 lo) split
// ---------------------------------------------------------------------------
__global__ __launch_bounds__(256)
void split_f32(const float* __restrict__ in, short* __restrict__ oh,
               short* __restrict__ ol, int n4)
{
    int i = blockIdx.x * 256 + threadIdx.x;
    if (i >= n4) return;
    float4 v = ((const float4*)in)[i];
    short h0 = f2bf(v.x), h1 = f2bf(v.y), h2 = f2bf(v.z), h3 = f2bf(v.w);
    short l0 = f2bf(v.x - bf2f(h0)), l1 = f2bf(v.y - bf2f(h1));
    short l2 = f2bf(v.z - bf2f(h2)), l3 = f2bf(v.w - bf2f(h3));
    ((short4*)oh)[i] = make_short4(h0, h1, h2, h3);
    ((short4*)ol)[i] = make_short4(l0, l1, l2, l3);
}

// ---------------------------------------------------------------------------
// Transpose + split: W[K][N] fp32 -> WT_h/WT_l [N][K] bf16 (ldo = K)
// ---------------------------------------------------------------------------
__global__ __launch_bounds__(256)
void transpose_split_f32(const float* __restrict__ W, int K, int N,
                         short* __restrict__ oth, short* __restrict__ otl, int ldo)
{
    __shared__ float tile[32][33];
    const int bx = blockIdx.x, by = blockIdx.y;       // bx over N, by over K
    const int c = threadIdx.x & 31, r = threadIdx.x >> 5;
    #pragma unroll
    for (int it = 0; it < 4; ++it)
        tile[r + it * 8][c] = W[(size_t)(by * 32 + r + it * 8) * N + bx * 32 + c];
    __syncthreads();
    #pragma unroll
    for (int it = 0; it < 4; ++it) {
        int n = bx * 32 + r + it * 8;
        int k = by * 32 + c;
        float v = tile[c][r + it * 8];
        short h = f2bf(v), l = f2bf(v - bf2f(h));
        oth[(size_t)n * ldo + k] = h;
        otl[(size_t)n * ldo + k] = l;
    }
}

// ---------------------------------------------------------------------------
// bf16 transpose: in[R][C] -> out[C][R]   (for V -> V^T)
// ---------------------------------------------------------------------------
__global__ __launch_bounds__(256)
void transpose_bf16(const short* __restrict__ in, int R, int C,
                    short* __restrict__ out)
{
    __shared__ short tile[32][33];
    const int bx = blockIdx.x, by = blockIdx.y;       // bx over C, by over R
    const int c = threadIdx.x & 31, r = threadIdx.x >> 5;
    #pragma unroll
    for (int it = 0; it < 4; ++it)
        tile[r + it * 8][c] = in[(size_t)(by * 32 + r + it * 8) * C + bx * 32 + c];
    __syncthreads();
    #pragma unroll
    for (int it = 0; it < 4; ++it)
        out[(size_t)(bx * 32 + r + it * 8) * R + by * 32 + c] = tile[c][r + it * 8];
}

// ---------------------------------------------------------------------------
// 3-term bf16 MFMA GEMM with SPLIT-K=2 (unchanged: at the 128x128/2-barrier
// structural ceiling, ~980 TF effective, 0 bank conflicts)
// ---------------------------------------------------------------------------
__global__ __launch_bounds__(256)
void gemm3s(const short* __restrict__ Ah, const short* __restrict__ Al,
            const short* __restrict__ Bh, const short* __restrict__ Bl,
            int K, int ldc, float* __restrict__ P)
{
    __shared__ __align__(16) short AhS[128 * 32];   // 32 KB total
    __shared__ __align__(16) short AlS[128 * 32];
    __shared__ __align__(16) short BhS[128 * 32];
    __shared__ __align__(16) short BlS[128 * 32];

    const int t = threadIdx.x, lane = t & 63, w = t >> 6;
    const int wr = (w >> 1) * 64, wc = (w & 1) * 64;
    const int m0 = blockIdx.y * 128, n0 = blockIdx.x * 128;
    const int kbase = blockIdx.z * (K >> 1);
    float* out = P + (size_t)blockIdx.z * ((size_t)gridDim.y * 128) * ldc;

    f32x4 zero = {0.f, 0.f, 0.f, 0.f};
    f32x4 acc[4][4];
    #pragma unroll
    for (int i = 0; i < 4; ++i)
        #pragma unroll
        for (int j = 0; j < 4; ++j) acc[i][j] = zero;

    const int sr0 = (w * 2 + 0) * 16 + (lane >> 2);
    const int sr1 = (w * 2 + 1) * 16 + (lane >> 2);
    const int sc0 = (((lane & 3) ^ ((sr0 >> 1) & 3)) * 8);   // 16B granule
    const int sc1 = (((lane & 3) ^ ((sr1 >> 1) & 3)) * 8);
    const size_t ga0 = (size_t)(m0 + sr0) * K + kbase + sc0;
    const size_t ga1 = (size_t)(m0 + sr1) * K + kbase + sc1;
    const size_t gb0 = (size_t)(n0 + sr0) * K + kbase + sc0;
    const size_t gb1 = (size_t)(n0 + sr1) * K + kbase + sc1;
    const int co0 = (w * 2 + 0) * 1024;
    const int co1 = (w * 2 + 1) * 1024;

    const int fr = lane & 15, fs = lane >> 4;

    const int nsteps = K >> 6;   // (K/2)/32
    for (int s = 0; s < nsteps; ++s) {
        const int k0 = s << 5;
        __syncthreads();
        gll16(Ah + ga0 + k0, (char*)AhS + co0);
        gll16(Ah + ga1 + k0, (char*)AhS + co1);
        gll16(Al + ga0 + k0, (char*)AlS + co0);
        gll16(Al + ga1 + k0, (char*)AlS + co1);
        gll16(Bh + gb0 + k0, (char*)BhS + co0);
        gll16(Bh + gb1 + k0, (char*)BhS + co1);
        gll16(Bl + gb0 + k0, (char*)BlS + co0);
        gll16(Bl + gb1 + k0, (char*)BlS + co1);
        __syncthreads();

        bf16x8 fah[4], fal[4], fbh[4], fbl[4];
        #pragma unroll
        for (int i = 0; i < 4; ++i) {
            int ar = wr + i * 16 + fr;
            int aoff = ar * 64 + ((fs ^ ((ar >> 1) & 3)) << 4);
            fah[i] = *(const bf16x8*)((const char*)AhS + aoff);
            fal[i] = *(const bf16x8*)((const char*)AlS + aoff);
            int br = wc + i * 16 + fr;
            int boff = br * 64 + ((fs ^ ((br >> 1) & 3)) << 4);
            fbh[i] = *(const bf16x8*)((const char*)BhS + boff);
            fbl[i] = *(const bf16x8*)((const char*)BlS + boff);
        }
        #pragma unroll
        for (int i = 0; i < 4; ++i)
            #pragma unroll
            for (int j = 0; j < 4; ++j) {
                acc[i][j] = __builtin_amdgcn_mfma_f32_16x16x32_bf16(fah[i], fbh[j], acc[i][j], 0, 0, 0);
                acc[i][j] = __builtin_amdgcn_mfma_f32_16x16x32_bf16(fah[i], fbl[j], acc[i][j], 0, 0, 0);
                acc[i][j] = __builtin_amdgcn_mfma_f32_16x16x32_bf16(fal[i], fbh[j], acc[i][j], 0, 0, 0);
            }
    }

    const int g = lane >> 4;
    #pragma unroll
    for (int i = 0; i < 4; ++i)
        #pragma unroll
        for (int j = 0; j < 4; ++j)
            #pragma unroll
            for (int r = 0; r < 4; ++r) {
                int m = m0 + wr + i * 16 + g * 4 + r;
                int n = n0 + wc + j * 16 + fr;
                out[(size_t)m * ldc + n] = acc[i][j][r];
            }
}

// ---------------------------------------------------------------------------
// Split-K reduce for QKV + RoPE epilogue + bf16 store to Q/K/V buffers.
// ---------------------------------------------------------------------------
__global__ __launch_bounds__(256)
void reduce_qkv(const float* __restrict__ P,
                const float* __restrict__ rs, const float* __restrict__ rc,
                short* __restrict__ Qo, short* __restrict__ Ko,
                short* __restrict__ Vo)
{
    const int idx = blockIdx.x * 256 + threadIdx.x;   // T*3072/8 threads
    const int row = idx / 384;                        // 3072/8 = 384
    const int c8  = (idx - row * 384) * 8;
    const float* p0 = P + (size_t)row * 3072 + c8;
    const float* p1 = p0 + (size_t)2048 * 3072;
    float4 a0 = *(const float4*)p0,       a1 = *(const float4*)(p0 + 4);
    float4 b0 = *(const float4*)p1,       b1 = *(const float4*)(p1 + 4);
    float v[8] = {a0.x + b0.x, a0.y + b0.y, a0.z + b0.z, a0.w + b0.w,
                  a1.x + b1.x, a1.y + b1.y, a1.z + b1.z, a1.w + b1.w};
    if (c8 < 2560) {   // RoPE region (Q | K)
        int pib = (c8 & 63) >> 1;
        #pragma unroll
        for (int j = 0; j < 4; ++j) {
            float sn = rs[row * (HDIM / 2) + pib + j];
            float cs = rc[row * (HDIM / 2) + pib + j];
            float e = v[2 * j], o = v[2 * j + 1];
            v[2 * j]     = e * cs - o * sn;
            v[2 * j + 1] = e * sn + o * cs;
        }
    }
    short s[8];
    #pragma unroll
    for (int j = 0; j < 8; ++j) s[j] = f2bf(v[j]);
    short4 lo = make_short4(s[0], s[1], s[2], s[3]);
    short4 hi = make_short4(s[4], s[5], s[6], s[7]);
    if (c8 < 2048) {
        short* q = Qo + (size_t)row * DMODEL + c8;
        *(short4*)q = lo; *(short4*)(q + 4) = hi;
    } else if (c8 < 2560) {
        short* k = Ko + (size_t)row * KVW + (c8 - 2048);
        *(short4*)k = lo; *(short4*)(k + 4) = hi;
    } else {
        short* vv = Vo + (size_t)row * KVW + (c8 - 2560);
        *(short4*)vv = lo; *(short4*)(vv + 4) = hi;
    }
}

// ---------------------------------------------------------------------------
// Split-K reduce for output projection: d_out = P0 + P1 (fp32)
// ---------------------------------------------------------------------------
__global__ __launch_bounds__(256)
void reduce_out(const float* __restrict__ P, float* __restrict__ out)
{
    const int i = (blockIdx.x * 256 + threadIdx.x) * 8;   // 2048*2048 elems
    const float* p1 = P + (size_t)2048 * 2048;
    float4 a0 = *(const float4*)(P + i),  a1 = *(const float4*)(P + i + 4);
    float4 b0 = *(const float4*)(p1 + i), b1 = *(const float4*)(p1 + i + 4);
    float4 o0 = make_float4(a0.x + b0.x, a0.y + b0.y, a0.z + b0.z, a0.w + b0.w);
    float4 o1 = make_float4(a1.x + b1.x, a1.y + b1.y, a1.z + b1.z, a1.w + b1.w);
    *(float4*)(out + i) = o0;
    *(float4*)(out + i + 4) = o1;
}

// ---------------------------------------------------------------------------
// Flash attention, bf16 MFMA, causal + SWA, GQA. KVBLK=64.
// STATIC-MAX softmax: P = exp2(s*0.125*log2e - 23.08). Softmax is
// shift-invariant; scores ~N(0,1), f32 exp overflow needs s>104 (impossible).
// Eliminates online max, per-tile O rescale, and ALL per-tile cross-lane
// reductions: l accumulates as per-lane partials, reduced once at the end.
// ---------------------------------------------------------------------------
__global__ __launch_bounds__(256)
void attn_mfma(const short* __restrict__ Qb, const short* __restrict__ Kb,
               const short* __restrict__ Vt, short* __restrict__ AoH,
               short* __restrict__ AoL, const int* __restrict__ swa_ptr, int T)
{
    __shared__ __align__(16) short Ks[2][64 * 64];   // 2 x 8 KB
    __shared__ __align__(16) short Vs[2][64 * 64];   // 2 x 8 KB
    __shared__ __align__(16) short Ps[4][16 * 64];   // 8 KB (per-wave 2KB)

    const int h = blockIdx.y, qt = blockIdx.x;
    const int q0 = qt * 64, hk = h >> 2;
    const int t = threadIdx.x, lane = t & 63, w = t >> 6;
    const int swa = *swa_ptr;
    const int fr = lane & 15, g = lane >> 4;
    const int qrow = q0 + w * 16;
    const float SCL2 = 0.18033688f;      // 0.125 * log2(e)
    const float SHFT = 23.083120f;       // 16 * log2(e)

    bf16x8 qf0, qf1;
    {
        const short* qp = Qb + (size_t)(qrow + fr) * DMODEL + h * HDIM + g * 8;
        qf0 = *(const bf16x8*)qp;
        qf1 = *(const bf16x8*)(qp + 32);
    }

    f32x4 zero = {0.f, 0.f, 0.f, 0.f};
    f32x4 oacc[4];
    #pragma unroll
    for (int dt = 0; dt < 4; ++dt) oacc[dt] = zero;
    float lreg[4] = {0.f, 0.f, 0.f, 0.f};   // per-lane partial row sums

    int kt_lo = 0;
    if (swa > 0) { int lo = q0 - swa; if (lo > 0) kt_lo = lo >> 6; }
    const int kt_hi = (q0 + 63) >> 6;

    // staging geometry: tile rows srow (+8 for 2nd chunk), 16B col granules
    const int srow = w * 16 + (lane >> 3);                  // 0..63
    const int scol = (((lane & 7) ^ (srow & 7)) * 8);       // pre-swizzled col
    const size_t kg0 = (size_t)srow * KVW + hk * HDIM + scol;
    const size_t kg1 = (size_t)(srow + 8) * KVW + hk * HDIM + scol;
    const size_t vg0 = (size_t)(hk * HDIM + srow) * T + scol;
    const size_t vg1 = (size_t)(hk * HDIM + srow + 8) * T + scol;

    auto stage = [&](int kt, int p) {
        const size_t koff = (size_t)(kt * 64) * KVW;
        gll16(Kb + koff + kg0, (char*)Ks[p] + w * 2048);
        gll16(Kb + koff + kg1, (char*)Ks[p] + w * 2048 + 1024);
        gll16(Vt + vg0 + kt * 64, (char*)Vs[p] + w * 2048);
        gll16(Vt + vg1 + kt * 64, (char*)Vs[p] + w * 2048 + 1024);
    };

    stage(kt_lo, 0);

    for (int kt = kt_lo; kt <= kt_hi; ++kt) {
        const int k0 = kt * 64;
        const int p = (kt - kt_lo) & 1;
        __syncthreads();                 // prefetch for kt landed
        if (kt + 1 <= kt_hi) stage(kt + 1, p ^ 1);

        // S = Q K^T over 4 16-key chunks x 2 d-halves
        f32x4 s[4];
        s[0] = zero; s[1] = zero; s[2] = zero; s[3] = zero;
        __builtin_amdgcn_s_setprio(1);
        #pragma unroll
        for (int c = 0; c < 4; ++c) {
            int key = c * 16 + fr;
            #pragma unroll
            for (int ks = 0; ks < 2; ++ks) {
                int slot = ks * 4 + g;
                bf16x8 kf = *(const bf16x8*)((const char*)Ks[p] + key * 128 + ((slot ^ (key & 7)) << 4));
                s[c] = __builtin_amdgcn_mfma_f32_16x16x32_bf16(ks ? qf1 : qf0, kf, s[c], 0, 0, 0);
            }
        }
        __builtin_amdgcn_s_setprio(0);

        const bool full = (k0 + 63 <= qrow) && (swa <= 0 || (qrow + 15 - k0) <= swa);

        // static-max softmax: no cross-lane ops, no O rescale
        #pragma unroll
        for (int r = 0; r < 4; ++r) {
            int i = qrow + g * 4 + r;
            int row = g * 4 + r;
            #pragma unroll
            for (int c = 0; c < 4; ++c) {
                float sv;
                if (full) {
                    sv = s[c][r] * SCL2;
                } else {
                    int j = k0 + c * 16 + fr;
                    int dl = i - j;
                    sv = (dl >= 0 && (swa <= 0 || dl <= swa)) ? s[c][r] * SCL2 : -INFINITY;
                }
                float pe = exp2f(sv - SHFT);
                lreg[r] += pe;
                int jj = c * 16 + fr;
                *(short*)((char*)Ps[w] + row * 128 + ((((jj >> 3) ^ (row & 7)) << 4)) + ((jj & 7) << 1)) = f2bf(pe);
            }
        }
        // Ps[w] wave-private: same-wave RAW ordered by lgkmcnt

        // PV over 2 32-key k-steps (no rescale needed)
        __builtin_amdgcn_s_setprio(1);
        #pragma unroll
        for (int c2 = 0; c2 < 2; ++c2) {
            bf16x8 pf = *(const bf16x8*)((const char*)Ps[w] + fr * 128 + (((c2 * 4 + g) ^ (fr & 7)) << 4));
            #pragma unroll
            for (int dt = 0; dt < 4; ++dt) {
                int d = dt * 16 + fr;
                bf16x8 vf = *(const bf16x8*)((const char*)Vs[p] + d * 128 + (((c2 * 4 + g) ^ (d & 7)) << 4));
                oacc[dt] = __builtin_amdgcn_mfma_f32_16x16x32_bf16(pf, vf, oacc[dt], 0, 0, 0);
            }
        }
        __builtin_amdgcn_s_setprio(0);
    }

    // single end-of-loop row-sum reduction (lanes sharing g hold row partials)
    float invl[4];
    #pragma unroll
    for (int r = 0; r < 4; ++r) {
        float ls = lreg[r];
        ls += __shfl_xor(ls, 1);
        ls += __shfl_xor(ls, 2);
        ls += __shfl_xor(ls, 4);
        ls += __shfl_xor(ls, 8);
        invl[r] = 1.0f / ls;
    }
    #pragma unroll
    for (int dt = 0; dt < 4; ++dt)
        #pragma unroll
        for (int r = 0; r < 4; ++r) {
            int i = qrow + g * 4 + r;
            float v = oacc[dt][r] * invl[r];
            int col = h * HDIM + dt * 16 + fr;
            short hb = f2bf(v);
            short lb = f2bf(v - bf2f(hb));
            AoH[(size_t)i * DMODEL + col] = hb;
            AoL[(size_t)i * DMODEL + col] = lb;
        }
}

// ---------------------------------------------------------------------------
extern "C" void kernel_launch(void* const* d_in, const int* in_sizes, int n_in,
                              void* d_out, int out_size, void* d_ws, size_t ws_size,
                              hipStream_t stream)
{
    const float* x    = (const float*)d_in[0];
    const float* Wq   = (const float*)d_in[1];
    const float* Wk   = (const float*)d_in[2];
    const float* Wv   = (const float*)d_in[3];
    const float* Wo   = (const float*)d_in[4];
    const float* rsin = (const float*)d_in[5];
    const float* rcos = (const float*)d_in[6];
    const int*   swa  = (const int*)d_in[7];

    const int T = in_sizes[0] / DMODEL;   // 2048 (B=1)

    char* p = (char*)d_ws;
    short* WTh  = (short*)p; p += (size_t)3072 * 2048 * 2;   // (Wq|Wk|Wv)^T hi
    short* WTl  = (short*)p; p += (size_t)3072 * 2048 * 2;
    short* WoTh = (short*)p; p += (size_t)2048 * 2048 * 2;
    short* WoTl = (short*)p; p += (size_t)2048 * 2048 * 2;
    short* Xh   = (short*)p; p += (size_t)T * DMODEL * 2;
    short* Xl   = (short*)p; p += (size_t)T * DMODEL * 2;
    short* Qbf  = (short*)p; p += (size_t)T * DMODEL * 2;
    short* Kbf  = (short*)p; p += (size_t)T * KVW * 2;
    short* Vbf  = (short*)p; p += (size_t)T * KVW * 2;
    short* Vt   = (short*)p; p += (size_t)T * KVW * 2;
    float* Part = (float*)p; p += (size_t)2 * T * 3072 * 4;  // split-K partials
    short* AoH  = Xh;   // alias: X dead after QKV gemm
    short* AoL  = Xl;

    // 1. split x into hi/lo bf16
    int n4 = T * DMODEL / 4;
    split_f32<<<(n4 + 255) / 256, 256, 0, stream>>>(x, Xh, Xl, n4);

    // 2. transpose+split weights into [N][K] bf16 hi/lo
    transpose_split_f32<<<dim3(2048 / 32, 2048 / 32), 256, 0, stream>>>(Wq, 2048, 2048, WTh, WTl, 2048);
    transpose_split_f32<<<dim3(512 / 32, 2048 / 32), 256, 0, stream>>>(Wk, 2048, 512, WTh + (size_t)2048 * 2048, WTl + (size_t)2048 * 2048, 2048);
    transpose_split_f32<<<dim3(512 / 32, 2048 / 32), 256, 0, stream>>>(Wv, 2048, 512, WTh + (size_t)2560 * 2048, WTl + (size_t)2560 * 2048, 2048);
    transpose_split_f32<<<dim3(2048 / 32, 2048 / 32), 256, 0, stream>>>(Wo, 2048, 2048, WoTh, WoTl, 2048);

    // 3. QKV projection, split-K=2 (768 blocks = 3/CU) -> fp32 partials
    gemm3s<<<dim3(3072 / 128, T / 128, 2), 256, 0, stream>>>(
        Xh, Xl, WTh, WTl, 2048, 3072, Part);
    // 3b. reduce + RoPE + bf16 -> Q/K/V
    reduce_qkv<<<T * 3072 / 8 / 256, 256, 0, stream>>>(Part, rsin, rcos, Qbf, Kbf, Vbf);

    // 4. V -> V^T [512][T]
    transpose_bf16<<<dim3(KVW / 32, T / 32), 256, 0, stream>>>(Vbf, T, KVW, Vt);

    // 5. attention (KVBLK=64, static-max softmax)
    attn_mfma<<<dim3(T / 64, NH), 256, 0, stream>>>(Qbf, Kbf, Vt, AoH, AoL, swa, T);

    // 6. output projection, split-K=2 (512 blocks = 2/CU) -> partials
    gemm3s<<<dim3(2048 / 128, T / 128, 2), 256, 0, stream>>>(
        AoH, AoL, WoTh, WoTl, 2048, 2048, Part);
    // 6b. reduce -> fp32 out
    reduce_out<<<T * 2048 / 8 / 256, 256, 0, stream>>>(Part, (float*)d_out);
}